// Round 5
// baseline (356.007 us; speedup 1.0000x reference)
//
#include <hip/hip_runtime.h>
#include <hip/hip_bf16.h>

// MoE: N=4096 tokens, D=512, H=2048, E=8 experts, top-2.
// Round 5: m97-style GEMM K-loop. (1) global_load_lds width-16 staging into
// unpadded 64-B LDS rows (lane-linear LDS dest; per-lane global addrs keep the
// token gather). (2) Swapped MFMA roles: W is the A/m operand so C/D holds 4
// consecutive h (gemm1) / d (gemm2) per lane -> packed 8-B H1 stores,
// consecutive-address atomics, float4 bias loads. Rest verified rounds 1-4.

#define N_TOK 4096
#define DIM   512
#define HID   2048
#define NEXP  8
#define TOTSLOT (2 * N_TOK)
#define MAXTILE 72

typedef __attribute__((ext_vector_type(8))) short short8;
typedef __attribute__((ext_vector_type(4))) float f32x4;

static __device__ __forceinline__ unsigned short f2bf(float f) {
    __hip_bfloat16 b = __float2bfloat16(f);
    return *reinterpret_cast<unsigned short*>(&b);
}

// 16-B direct global->LDS (gfx950 global_load_lds_dwordx4). LDS dest must be
// wave-uniform base + lane*16 — our tid->LDS map satisfies this by layout.
static __device__ __forceinline__ void load16_to_lds(const void* g, void* l) {
    __builtin_amdgcn_global_load_lds(
        (const __attribute__((address_space(1))) unsigned int*)g,
        (__attribute__((address_space(3))) unsigned int*)l, 16, 0, 0);
}

// ---------------------------------------------------------------- gating ----
__global__ __launch_bounds__(256) void gating_kernel(
    const float* __restrict__ x, const float* __restrict__ Wg,
    const float* __restrict__ bg,
    int* __restrict__ cnt, int* __restrict__ te, float* __restrict__ tw,
    float* __restrict__ usage)
{
    __shared__ int   lcnt[NEXP];
    __shared__ float lus[NEXP];
    int tid = threadIdx.x;
    if (tid < NEXP) { lcnt[tid] = 0; lus[tid] = 0.f; }
    __syncthreads();

    int wave = tid >> 6;
    int lane = tid & 63;

    for (int t = 0; t < 16; ++t) {
        int n = blockIdx.x * 64 + wave * 16 + t;

        float acc[NEXP];
#pragma unroll
        for (int e = 0; e < NEXP; ++e) acc[e] = 0.f;

#pragma unroll
        for (int it = 0; it < DIM / 64; ++it) {
            int d = it * 64 + lane;
            float xv = x[n * DIM + d];
            float4 wa = *(const float4*)&Wg[d * NEXP];
            float4 wb = *(const float4*)&Wg[d * NEXP + 4];
            acc[0] += xv * wa.x; acc[1] += xv * wa.y;
            acc[2] += xv * wa.z; acc[3] += xv * wa.w;
            acc[4] += xv * wb.x; acc[5] += xv * wb.y;
            acc[6] += xv * wb.z; acc[7] += xv * wb.w;
        }
#pragma unroll
        for (int m = 32; m >= 1; m >>= 1) {
#pragma unroll
            for (int e = 0; e < NEXP; ++e)
                acc[e] += __shfl_xor(acc[e], m, 64);
        }
        if (lane == 0) {
            float l[NEXP];
#pragma unroll
            for (int e = 0; e < NEXP; ++e) l[e] = acc[e] + bg[e];
            int i0 = 0;
#pragma unroll
            for (int e = 1; e < NEXP; ++e) if (l[e] > l[i0]) i0 = e;
            int i1 = (i0 == 0) ? 1 : 0;
#pragma unroll
            for (int e = 0; e < NEXP; ++e)
                if (e != i0 && l[e] > l[i1]) i1 = e;
            float w0 = 1.f / (1.f + expf(l[i1] - l[i0]));
            float w1 = 1.f - w0;
            te[n * 2] = i0; te[n * 2 + 1] = i1;
            tw[n * 2] = w0; tw[n * 2 + 1] = w1;
            atomicAdd(&lcnt[i0], 1);
            atomicAdd(&lcnt[i1], 1);
            atomicAdd(&lus[i0], w0);
            atomicAdd(&lus[i1], w1);
        }
    }
    __syncthreads();
    if (tid < NEXP) {
        if (lcnt[tid]) atomicAdd(&cnt[tid], lcnt[tid]);
        if (lus[tid] != 0.f) atomicAdd(&usage[tid], lus[tid]);
    }
}

__global__ void prefix_kernel(const int* __restrict__ cnt,
                              int* __restrict__ offs, int* __restrict__ fill,
                              unsigned short* __restrict__ tile_tab,
                              int* __restrict__ ntile)
{
    if (threadIdx.x == 0) {
        int s = 0, nt = 0;
        for (int e = 0; e < NEXP; ++e) {
            offs[e] = s; s += cnt[e];
            int t = (cnt[e] + 127) >> 7;
            for (int i = 0; i < t; ++i)
                tile_tab[nt++] = (unsigned short)((e << 8) | i);
        }
        *ntile = nt;
        for (int i = nt; i < MAXTILE; ++i) tile_tab[i] = 0;
    }
    if (threadIdx.x < NEXP) fill[threadIdx.x] = 0;
}

__global__ __launch_bounds__(256) void scatter_kernel(
    const int* __restrict__ te, const float* __restrict__ tw,
    const int* __restrict__ offs, int* __restrict__ fill,
    int* __restrict__ btok, float* __restrict__ bwt)
{
    __shared__ int lcnt[NEXP];
    __shared__ int gbase[NEXP];
    int tid = threadIdx.x;
    if (tid < NEXP) lcnt[tid] = 0;
    __syncthreads();
    int n = blockIdx.x * 256 + tid;
    int e0 = te[n * 2], e1 = te[n * 2 + 1];
    int l0 = atomicAdd(&lcnt[e0], 1);
    int l1 = atomicAdd(&lcnt[e1], 1);
    __syncthreads();
    if (tid < NEXP) gbase[tid] = atomicAdd(&fill[tid], lcnt[tid]);
    __syncthreads();
    int s0 = offs[e0] + gbase[e0] + l0;
    int s1 = offs[e1] + gbase[e1] + l1;
    btok[s0] = n; bwt[s0] = tw[n * 2];
    btok[s1] = n; bwt[s1] = tw[n * 2 + 1];
}

// ----------------------------------------------------------- conversions ----
__global__ __launch_bounds__(256) void cvtx_kernel(
    const float* __restrict__ x, unsigned short* __restrict__ Xb)
{
    int i = (blockIdx.x * 256 + threadIdx.x) * 4;
    float4 v = *(const float4*)&x[i];
    ushort4 u;
    u.x = f2bf(v.x); u.y = f2bf(v.y); u.z = f2bf(v.z); u.w = f2bf(v.w);
    *(ushort4*)&Xb[i] = u;
}

// in: [E][R][C] fp32  ->  out: [E][C][R] bf16
__global__ __launch_bounds__(256) void transpose_cvt_kernel(
    const float* __restrict__ in, unsigned short* __restrict__ out,
    int R, int C)
{
    __shared__ unsigned short tile[64][65];
    int e = blockIdx.z;
    const float* src = in + (size_t)e * R * C;
    unsigned short* dst = out + (size_t)e * R * C;
    int r0 = blockIdx.x * 64, c0 = blockIdx.y * 64;
    int tid = threadIdx.x;
    int rr = tid >> 2, cb = (tid & 3) * 16;
#pragma unroll
    for (int i = 0; i < 4; ++i) {
        float4 v = *(const float4*)&src[(size_t)(r0 + rr) * C + c0 + cb + i * 4];
        tile[rr][cb + i * 4 + 0] = f2bf(v.x);
        tile[rr][cb + i * 4 + 1] = f2bf(v.y);
        tile[rr][cb + i * 4 + 2] = f2bf(v.z);
        tile[rr][cb + i * 4 + 3] = f2bf(v.w);
    }
    __syncthreads();
#pragma unroll
    for (int i = 0; i < 4; ++i) {
        ushort4 u;
        u.x = tile[cb + i * 4 + 0][rr];
        u.y = tile[cb + i * 4 + 1][rr];
        u.z = tile[cb + i * 4 + 2][rr];
        u.w = tile[cb + i * 4 + 3][rr];
        *(ushort4*)&dst[(size_t)(c0 + rr) * R + r0 + cb + i * 4] = u;
    }
}

// ------------------------------------------------------------- MFMA GEMM ----
// LDS tiles: 128 rows x 32 bf16, UNPADDED 64-B rows (global_load_lds needs
// lane-linear dest). Ws = A operand (m = h or d), Xs/Hs = B operand (n =
// token/slot). C/D: col(lane&15) = n, row(quad*4+r) = m -> lane's 4 acc
// values are 4 consecutive m (h/d) for one n.

__global__ __launch_bounds__(256) void gemm1_kernel(
    const unsigned short* __restrict__ Xb, const unsigned short* __restrict__ W1t,
    const float* __restrict__ b1, const int* __restrict__ cnt,
    const int* __restrict__ offs, const int* __restrict__ btok,
    const unsigned short* __restrict__ tile_tab, const int* __restrict__ ntile,
    unsigned short* __restrict__ H1)
{
    __shared__ __align__(16) unsigned short Ws[128 * 32];  // W1t rows (h)
    __shared__ __align__(16) unsigned short Xs[128 * 32];  // X rows (tokens)
    __shared__ int tok_s[128];

    int ti = blockIdx.x;
    if (ti >= *ntile) return;
    unsigned short tv = tile_tab[ti];
    int e = tv >> 8, tt = tv & 255, ht = blockIdx.y;
    int cn = cnt[e];
    int off_e = offs[e];
    int tid = threadIdx.x;

    if (tid < 128) {
        int lr = tt * 128 + tid;
        tok_s[tid] = (lr < cn) ? btok[off_e + lr] : 0;
    }
    __syncthreads();

    int wave = tid >> 6, lane = tid & 63;
    int mbase = (wave >> 1) * 64, nbase = (wave & 1) * 64;
    f32x4 acc[4][4];
#pragma unroll
    for (int mi = 0; mi < 4; ++mi)
#pragma unroll
        for (int ni = 0; ni < 4; ++ni)
            acc[mi][ni] = (f32x4){0.f, 0.f, 0.f, 0.f};

    int R0 = tid >> 2, cb = (tid & 3) * 8;     // row 0..63, 16-B chunk
    const unsigned short* Wsrc = W1t + ((size_t)e * HID + ht * 128) * DIM;
    int ka = (lane >> 4) * 8;
    int lcol = lane & 15;

    for (int k0 = 0; k0 < DIM; k0 += 32) {
#pragma unroll
        for (int p = 0; p < 2; ++p) {
            int R = R0 + p * 64;
            load16_to_lds(&Wsrc[(size_t)R * DIM + k0 + cb], &Ws[R * 32 + cb]);
            load16_to_lds(&Xb[(size_t)tok_s[R] * DIM + k0 + cb], &Xs[R * 32 + cb]);
        }
        __syncthreads();
        short8 a[4], b[4];
#pragma unroll
        for (int i = 0; i < 4; ++i) {
            a[i] = *(const short8*)&Ws[(mbase + i * 16 + lcol) * 32 + ka];
            b[i] = *(const short8*)&Xs[(nbase + i * 16 + lcol) * 32 + ka];
        }
#pragma unroll
        for (int mi = 0; mi < 4; ++mi)
#pragma unroll
            for (int ni = 0; ni < 4; ++ni)
                acc[mi][ni] = __builtin_amdgcn_mfma_f32_16x16x32_bf16(
                    a[mi], b[ni], acc[mi][ni], 0, 0, 0);
        __syncthreads();
    }

    int quad = lane >> 4;
    float4 bv[4];
#pragma unroll
    for (int mi = 0; mi < 4; ++mi)
        bv[mi] = *(const float4*)&b1[e * HID + ht * 128 + mbase + mi * 16 + quad * 4];
#pragma unroll
    for (int ni = 0; ni < 4; ++ni) {
        int tn = tt * 128 + nbase + ni * 16 + lcol;      // slot row in expert
        if (tn >= cn) continue;
        size_t srow = (size_t)(off_e + tn) * HID + ht * 128;
#pragma unroll
        for (int mi = 0; mi < 4; ++mi) {
            int h = mbase + mi * 16 + quad * 4;
            ushort4 u;
            u.x = f2bf(acc[mi][ni][0] + bv[mi].x);
            u.y = f2bf(acc[mi][ni][1] + bv[mi].y);
            u.z = f2bf(acc[mi][ni][2] + bv[mi].z);
            u.w = f2bf(acc[mi][ni][3] + bv[mi].w);
            *(ushort4*)&H1[srow + h] = u;
        }
    }
}

#define KSPLIT 2
#define KCH (HID / KSPLIT)

__global__ __launch_bounds__(256) void gemm2_kernel(
    const unsigned short* __restrict__ H1, const unsigned short* __restrict__ W2t,
    const float* __restrict__ b2, const int* __restrict__ cnt,
    const int* __restrict__ offs, const int* __restrict__ btok,
    const float* __restrict__ bwt,
    const unsigned short* __restrict__ tile_tab, const int* __restrict__ ntile,
    float* __restrict__ out)
{
    __shared__ __align__(16) unsigned short Ws[128 * 32];  // W2t rows (d)
    __shared__ __align__(16) unsigned short Hs[128 * 32];  // H1 rows (slots)
    __shared__ int   tok_s[128];
    __shared__ float wt_s[128];

    int ti = blockIdx.x;
    if (ti >= *ntile) return;
    unsigned short tv = tile_tab[ti];
    int e = tv >> 8, tt = tv & 255, dt = blockIdx.y, kz = blockIdx.z;
    int cn = cnt[e];
    int off_e = offs[e];
    int sb = off_e + tt * 128;
    int tid = threadIdx.x;

    if (tid < 128) {
        int lr = tt * 128 + tid;
        if (lr < cn) { tok_s[tid] = btok[off_e + lr]; wt_s[tid] = bwt[off_e + lr]; }
        else         { tok_s[tid] = 0;               wt_s[tid] = 0.f; }
    }
    __syncthreads();

    int wave = tid >> 6, lane = tid & 63;
    int mbase = (wave >> 1) * 64, nbase = (wave & 1) * 64;
    f32x4 acc[4][4];
#pragma unroll
    for (int mi = 0; mi < 4; ++mi)
#pragma unroll
        for (int ni = 0; ni < 4; ++ni)
            acc[mi][ni] = (f32x4){0.f, 0.f, 0.f, 0.f};

    int R0 = tid >> 2, cb = (tid & 3) * 8;
    const unsigned short* Wsrc = W2t + ((size_t)e * DIM + dt * 128) * HID;
    int ka = (lane >> 4) * 8;
    int lcol = lane & 15;

    for (int k0 = kz * KCH; k0 < (kz + 1) * KCH; k0 += 32) {
#pragma unroll
        for (int p = 0; p < 2; ++p) {
            int R = R0 + p * 64;
            int sr = sb + R; if (sr > TOTSLOT - 1) sr = TOTSLOT - 1;
            load16_to_lds(&Wsrc[(size_t)R * HID + k0 + cb], &Ws[R * 32 + cb]);
            load16_to_lds(&H1[(size_t)sr * HID + k0 + cb], &Hs[R * 32 + cb]);
        }
        __syncthreads();
        short8 a[4], b[4];
#pragma unroll
        for (int i = 0; i < 4; ++i) {
            a[i] = *(const short8*)&Ws[(mbase + i * 16 + lcol) * 32 + ka];
            b[i] = *(const short8*)&Hs[(nbase + i * 16 + lcol) * 32 + ka];
        }
#pragma unroll
        for (int mi = 0; mi < 4; ++mi)
#pragma unroll
            for (int ni = 0; ni < 4; ++ni)
                acc[mi][ni] = __builtin_amdgcn_mfma_f32_16x16x32_bf16(
                    a[mi], b[ni], acc[mi][ni], 0, 0, 0);
        __syncthreads();
    }

    int quad = lane >> 4;
    float4 bv[4];
#pragma unroll
    for (int mi = 0; mi < 4; ++mi) {
        if (kz == 0)
            bv[mi] = *(const float4*)&b2[e * DIM + dt * 128 + mbase + mi * 16 + quad * 4];
        else
            bv[mi] = make_float4(0.f, 0.f, 0.f, 0.f);
    }
#pragma unroll
    for (int ni = 0; ni < 4; ++ni) {
        int sl = nbase + ni * 16 + lcol;                 // slot within tile
        if (tt * 128 + sl >= cn) continue;
        float w = wt_s[sl];
        float* orow = &out[(size_t)tok_s[sl] * DIM + dt * 128];
#pragma unroll
        for (int mi = 0; mi < 4; ++mi) {
            int d = mbase + mi * 16 + quad * 4;
            atomicAdd(&orow[d + 0], w * (acc[mi][ni][0] + bv[mi].x));
            atomicAdd(&orow[d + 1], w * (acc[mi][ni][1] + bv[mi].y));
            atomicAdd(&orow[d + 2], w * (acc[mi][ni][2] + bv[mi].z));
            atomicAdd(&orow[d + 3], w * (acc[mi][ni][3] + bv[mi].w));
        }
    }
}

// ------------------------------------------------- round-1 fp32 fallback ----
#define TN 16
#define HC 256
#define NCHUNK (HID / HC)

__global__ __launch_bounds__(256) void gating_fb_kernel(
    const float* __restrict__ x, const float* __restrict__ Wg,
    const float* __restrict__ bg,
    int* __restrict__ cnt, int* __restrict__ btok, float* __restrict__ bwt,
    float* __restrict__ usage)
{
    int wave = threadIdx.x >> 6;
    int lane = threadIdx.x & 63;
    int n = blockIdx.x * 4 + wave;
    float acc[NEXP];
#pragma unroll
    for (int e = 0; e < NEXP; ++e) acc[e] = 0.f;
    for (int d = lane; d < DIM; d += 64) {
        float xv = x[n * DIM + d];
        float4 wa = *(const float4*)&Wg[d * NEXP];
        float4 wb = *(const float4*)&Wg[d * NEXP + 4];
        acc[0] += xv * wa.x; acc[1] += xv * wa.y;
        acc[2] += xv * wa.z; acc[3] += xv * wa.w;
        acc[4] += xv * wb.x; acc[5] += xv * wb.y;
        acc[6] += xv * wb.z; acc[7] += xv * wb.w;
    }
#pragma unroll
    for (int m = 32; m >= 1; m >>= 1)
#pragma unroll
        for (int e = 0; e < NEXP; ++e)
            acc[e] += __shfl_xor(acc[e], m, 64);
    if (lane == 0) {
        float l[NEXP];
#pragma unroll
        for (int e = 0; e < NEXP; ++e) l[e] = acc[e] + bg[e];
        int i0 = 0;
#pragma unroll
        for (int e = 1; e < NEXP; ++e) if (l[e] > l[i0]) i0 = e;
        int i1 = (i0 == 0) ? 1 : 0;
#pragma unroll
        for (int e = 0; e < NEXP; ++e)
            if (e != i0 && l[e] > l[i1]) i1 = e;
        float w0 = 1.f / (1.f + expf(l[i1] - l[i0]));
        float w1 = 1.f - w0;
        int p0 = atomicAdd(&cnt[i0], 1);
        btok[i0 * N_TOK + p0] = n; bwt[i0 * N_TOK + p0] = w0;
        int p1 = atomicAdd(&cnt[i1], 1);
        btok[i1 * N_TOK + p1] = n; bwt[i1 * N_TOK + p1] = w1;
        atomicAdd(&usage[i0], w0);
        atomicAdd(&usage[i1], w1);
    }
}

__global__ __launch_bounds__(256) void expert_fb_kernel(
    const float* __restrict__ x, const float* __restrict__ W1,
    const float* __restrict__ b1, const float* __restrict__ W2,
    const float* __restrict__ b2, const int* __restrict__ cnt,
    const int* __restrict__ btok, const float* __restrict__ bwt,
    float* __restrict__ out)
{
    __shared__ float xs[TN][DIM];
    __shared__ float h1s[TN][HC];
    __shared__ int   tok_s[TN];
    __shared__ float wt_s[TN];
    int e = blockIdx.x >> 8;
    int tile = blockIdx.x & 255;
    int cn = cnt[e];
    int n0 = tile * TN;
    if (n0 >= cn) return;
    int nt = min(TN, cn - n0);
    int tid = threadIdx.x;
    if (tid < TN) {
        if (tid < nt) { tok_s[tid] = btok[e * N_TOK + n0 + tid]; wt_s[tid] = bwt[e * N_TOK + n0 + tid]; }
        else          { tok_s[tid] = 0; wt_s[tid] = 0.f; }
    }
    __syncthreads();
    for (int idx = tid; idx < TN * DIM; idx += 256) {
        int t = idx >> 9, d = idx & 511;
        xs[t][d] = (t < nt) ? x[tok_s[t] * DIM + d] : 0.f;
    }
    const float* W1e = W1 + (size_t)e * DIM * HID;
    const float* W2e = W2 + (size_t)e * HID * DIM;
    int tg = tid >> 6, lane = tid & 63;
    float oacc[4][8];
    {
        float4 ba = *(const float4*)&b2[e * DIM + lane * 8];
        float4 bb = *(const float4*)&b2[e * DIM + lane * 8 + 4];
#pragma unroll
        for (int ti = 0; ti < 4; ++ti) {
            oacc[ti][0] = ba.x; oacc[ti][1] = ba.y; oacc[ti][2] = ba.z; oacc[ti][3] = ba.w;
            oacc[ti][4] = bb.x; oacc[ti][5] = bb.y; oacc[ti][6] = bb.z; oacc[ti][7] = bb.w;
        }
    }
    __syncthreads();
    for (int ch = 0; ch < NCHUNK; ++ch) {
        int h0 = ch * HC;
        float f[4][4];
        {
            float4 b1v = *(const float4*)&b1[e * HID + h0 + lane * 4];
#pragma unroll
            for (int ti = 0; ti < 4; ++ti) {
                f[ti][0] = b1v.x; f[ti][1] = b1v.y; f[ti][2] = b1v.z; f[ti][3] = b1v.w;
            }
        }
        for (int d = 0; d < DIM; ++d) {
            float4 w1v = *(const float4*)&W1e[(size_t)d * HID + h0 + lane * 4];
#pragma unroll
            for (int ti = 0; ti < 4; ++ti) {
                float xv = xs[tg + 4 * ti][d];
                f[ti][0] += xv * w1v.x; f[ti][1] += xv * w1v.y;
                f[ti][2] += xv * w1v.z; f[ti][3] += xv * w1v.w;
            }
        }
        __syncthreads();
#pragma unroll
        for (int ti = 0; ti < 4; ++ti)
            *(float4*)&h1s[tg + 4 * ti][lane * 4] = make_float4(f[ti][0], f[ti][1], f[ti][2], f[ti][3]);
        __syncthreads();
        for (int j = 0; j < HC; ++j) {
            const float* w2row = &W2e[(size_t)(h0 + j) * DIM + lane * 8];
            float4 wa = *(const float4*)w2row;
            float4 wb = *(const float4*)(w2row + 4);
#pragma unroll
            for (int ti = 0; ti < 4; ++ti) {
                float hv = h1s[tg + 4 * ti][j];
                oacc[ti][0] += hv * wa.x; oacc[ti][1] += hv * wa.y;
                oacc[ti][2] += hv * wa.z; oacc[ti][3] += hv * wa.w;
                oacc[ti][4] += hv * wb.x; oacc[ti][5] += hv * wb.y;
                oacc[ti][6] += hv * wb.z; oacc[ti][7] += hv * wb.w;
            }
        }
    }
#pragma unroll
    for (int ti = 0; ti < 4; ++ti) {
        int t = tg + 4 * ti;
        if (t < nt) {
            float w = wt_s[t];
            float* o = &out[(size_t)tok_s[t] * DIM + lane * 8];
#pragma unroll
            for (int c = 0; c < 8; ++c)
                atomicAdd(&o[c], w * oacc[ti][c]);
        }
    }
}

// ------------------------------------------------------------------ host ----
extern "C" void kernel_launch(void* const* d_in, const int* in_sizes, int n_in,
                              void* d_out, int out_size, void* d_ws, size_t ws_size,
                              hipStream_t stream) {
    const float* x  = (const float*)d_in[0];
    const float* Wg = (const float*)d_in[1];
    const float* bg = (const float*)d_in[2];
    const float* W1 = (const float*)d_in[3];
    const float* b1 = (const float*)d_in[4];
    const float* W2 = (const float*)d_in[5];
    const float* b2 = (const float*)d_in[6];

    float* out   = (float*)d_out;
    float* usage = out + (size_t)N_TOK * DIM;

    // ws layout (bf16 path)
    char* ws = (char*)d_ws;
    int*   cnt  = (int*)(ws + 0);
    int*   fill = (int*)(ws + 32);
    int*   offs = (int*)(ws + 64);
    unsigned short* tile_tab = (unsigned short*)(ws + 96);
    int*   ntile = (int*)(ws + 240);
    int*   te   = (int*)(ws + 256);
    float* tw   = (float*)(ws + 33024);
    int*   btok = (int*)(ws + 65792);
    float* bwt  = (float*)(ws + 98560);
    unsigned short* Xb  = (unsigned short*)(ws + 131328);
    unsigned short* W1t = (unsigned short*)(ws + 4325632);
    unsigned short* W2t = (unsigned short*)(ws + 21102848);
    unsigned short* H1  = (unsigned short*)(ws + 37880064);
    const size_t WS_NEED = 71434496ULL;

    hipMemsetAsync(d_out, 0, (size_t)(N_TOK * DIM + NEXP) * sizeof(float), stream);

    if (ws_size >= WS_NEED) {
        hipMemsetAsync(cnt, 0, 32, stream);
        cvtx_kernel<<<N_TOK * DIM / 1024, 256, 0, stream>>>(x, Xb);
        transpose_cvt_kernel<<<dim3(DIM / 64, HID / 64, NEXP), 256, 0, stream>>>(W1, W1t, DIM, HID);
        transpose_cvt_kernel<<<dim3(HID / 64, DIM / 64, NEXP), 256, 0, stream>>>(W2, W2t, HID, DIM);
        gating_kernel<<<N_TOK / 64, 256, 0, stream>>>(x, Wg, bg, cnt, te, tw, usage);
        prefix_kernel<<<1, 64, 0, stream>>>(cnt, offs, fill, tile_tab, ntile);
        scatter_kernel<<<N_TOK / 256, 256, 0, stream>>>(te, tw, offs, fill, btok, bwt);
        gemm1_kernel<<<dim3(MAXTILE, HID / 128), 256, 0, stream>>>(
            Xb, W1t, b1, cnt, offs, btok, tile_tab, ntile, H1);
        gemm2_kernel<<<dim3(MAXTILE, DIM / 128, KSPLIT), 256, 0, stream>>>(
            H1, W2t, b2, cnt, offs, btok, bwt, tile_tab, ntile, out);
    } else {
        // round-1 fp32 fallback (verified)
        int*   fcnt  = (int*)d_ws;
        int*   fbtok = (int*)((char*)d_ws + 256);
        float* fbwt  = (float*)((char*)d_ws + 256 + (size_t)NEXP * N_TOK * sizeof(int));
        hipMemsetAsync(d_ws, 0, 256, stream);
        gating_fb_kernel<<<N_TOK / 4, 256, 0, stream>>>(x, Wg, bg, fcnt, fbtok, fbwt, usage);
        expert_fb_kernel<<<NEXP * (N_TOK / TN), 256, 0, stream>>>(
            x, W1, b1, W2, b2, fcnt, fbtok, fbwt, out);
    }
}

// Round 6
// 281.466 us; speedup vs baseline: 1.2648x; 1.2648x over previous
//
#include <hip/hip_runtime.h>
#include <hip/hip_bf16.h>

// MoE: N=4096 tokens, D=512, H=2048, E=8 experts, top-2.
// Round 6: revert gemm2 operand roles to round-4 geometry (A=H1 slots,
// B=W2t d-rows). Round-5's swap made each 64-B out[] line receive its 16
// atomics across 4 instructions (4 lanes each, 16-B stride) instead of 1
// instruction (16 consecutive lanes) -> 4x L2 RMW transactions on a 134-MB
// atomic stream -> gemm2 72->144 us. Keep round-5 global_load_lds staging in
// both GEMMs and round-5 gemm1 (packed ushort4 H1 stores, left top-5).

#define N_TOK 4096
#define DIM   512
#define HID   2048
#define NEXP  8
#define TOTSLOT (2 * N_TOK)
#define MAXTILE 72

typedef __attribute__((ext_vector_type(8))) short short8;
typedef __attribute__((ext_vector_type(4))) float f32x4;

static __device__ __forceinline__ unsigned short f2bf(float f) {
    __hip_bfloat16 b = __float2bfloat16(f);
    return *reinterpret_cast<unsigned short*>(&b);
}

// 16-B direct global->LDS (gfx950 global_load_lds_dwordx4). LDS dest is
// wave-uniform base + lane*16 by construction of the tid->offset map.
static __device__ __forceinline__ void load16_to_lds(const void* g, void* l) {
    __builtin_amdgcn_global_load_lds(
        (const __attribute__((address_space(1))) unsigned int*)g,
        (__attribute__((address_space(3))) unsigned int*)l, 16, 0, 0);
}

// ---------------------------------------------------------------- gating ----
__global__ __launch_bounds__(256) void gating_kernel(
    const float* __restrict__ x, const float* __restrict__ Wg,
    const float* __restrict__ bg,
    int* __restrict__ cnt, int* __restrict__ te, float* __restrict__ tw,
    float* __restrict__ usage)
{
    __shared__ int   lcnt[NEXP];
    __shared__ float lus[NEXP];
    int tid = threadIdx.x;
    if (tid < NEXP) { lcnt[tid] = 0; lus[tid] = 0.f; }
    __syncthreads();

    int wave = tid >> 6;
    int lane = tid & 63;

    for (int t = 0; t < 16; ++t) {
        int n = blockIdx.x * 64 + wave * 16 + t;

        float acc[NEXP];
#pragma unroll
        for (int e = 0; e < NEXP; ++e) acc[e] = 0.f;

#pragma unroll
        for (int it = 0; it < DIM / 64; ++it) {
            int d = it * 64 + lane;
            float xv = x[n * DIM + d];
            float4 wa = *(const float4*)&Wg[d * NEXP];
            float4 wb = *(const float4*)&Wg[d * NEXP + 4];
            acc[0] += xv * wa.x; acc[1] += xv * wa.y;
            acc[2] += xv * wa.z; acc[3] += xv * wa.w;
            acc[4] += xv * wb.x; acc[5] += xv * wb.y;
            acc[6] += xv * wb.z; acc[7] += xv * wb.w;
        }
#pragma unroll
        for (int m = 32; m >= 1; m >>= 1) {
#pragma unroll
            for (int e = 0; e < NEXP; ++e)
                acc[e] += __shfl_xor(acc[e], m, 64);
        }
        if (lane == 0) {
            float l[NEXP];
#pragma unroll
            for (int e = 0; e < NEXP; ++e) l[e] = acc[e] + bg[e];
            int i0 = 0;
#pragma unroll
            for (int e = 1; e < NEXP; ++e) if (l[e] > l[i0]) i0 = e;
            int i1 = (i0 == 0) ? 1 : 0;
#pragma unroll
            for (int e = 0; e < NEXP; ++e)
                if (e != i0 && l[e] > l[i1]) i1 = e;
            float w0 = 1.f / (1.f + expf(l[i1] - l[i0]));
            float w1 = 1.f - w0;
            te[n * 2] = i0; te[n * 2 + 1] = i1;
            tw[n * 2] = w0; tw[n * 2 + 1] = w1;
            atomicAdd(&lcnt[i0], 1);
            atomicAdd(&lcnt[i1], 1);
            atomicAdd(&lus[i0], w0);
            atomicAdd(&lus[i1], w1);
        }
    }
    __syncthreads();
    if (tid < NEXP) {
        if (lcnt[tid]) atomicAdd(&cnt[tid], lcnt[tid]);
        if (lus[tid] != 0.f) atomicAdd(&usage[tid], lus[tid]);
    }
}

__global__ void prefix_kernel(const int* __restrict__ cnt,
                              int* __restrict__ offs, int* __restrict__ fill,
                              unsigned short* __restrict__ tile_tab,
                              int* __restrict__ ntile)
{
    if (threadIdx.x == 0) {
        int s = 0, nt = 0;
        for (int e = 0; e < NEXP; ++e) {
            offs[e] = s; s += cnt[e];
            int t = (cnt[e] + 127) >> 7;
            for (int i = 0; i < t; ++i)
                tile_tab[nt++] = (unsigned short)((e << 8) | i);
        }
        *ntile = nt;
        for (int i = nt; i < MAXTILE; ++i) tile_tab[i] = 0;
    }
    if (threadIdx.x < NEXP) fill[threadIdx.x] = 0;
}

__global__ __launch_bounds__(256) void scatter_kernel(
    const int* __restrict__ te, const float* __restrict__ tw,
    const int* __restrict__ offs, int* __restrict__ fill,
    int* __restrict__ btok, float* __restrict__ bwt)
{
    __shared__ int lcnt[NEXP];
    __shared__ int gbase[NEXP];
    int tid = threadIdx.x;
    if (tid < NEXP) lcnt[tid] = 0;
    __syncthreads();
    int n = blockIdx.x * 256 + tid;
    int e0 = te[n * 2], e1 = te[n * 2 + 1];
    int l0 = atomicAdd(&lcnt[e0], 1);
    int l1 = atomicAdd(&lcnt[e1], 1);
    __syncthreads();
    if (tid < NEXP) gbase[tid] = atomicAdd(&fill[tid], lcnt[tid]);
    __syncthreads();
    int s0 = offs[e0] + gbase[e0] + l0;
    int s1 = offs[e1] + gbase[e1] + l1;
    btok[s0] = n; bwt[s0] = tw[n * 2];
    btok[s1] = n; bwt[s1] = tw[n * 2 + 1];
}

// ----------------------------------------------------------- conversions ----
__global__ __launch_bounds__(256) void cvtx_kernel(
    const float* __restrict__ x, unsigned short* __restrict__ Xb)
{
    int i = (blockIdx.x * 256 + threadIdx.x) * 4;
    float4 v = *(const float4*)&x[i];
    ushort4 u;
    u.x = f2bf(v.x); u.y = f2bf(v.y); u.z = f2bf(v.z); u.w = f2bf(v.w);
    *(ushort4*)&Xb[i] = u;
}

// in: [E][R][C] fp32  ->  out: [E][C][R] bf16
__global__ __launch_bounds__(256) void transpose_cvt_kernel(
    const float* __restrict__ in, unsigned short* __restrict__ out,
    int R, int C)
{
    __shared__ unsigned short tile[64][65];
    int e = blockIdx.z;
    const float* src = in + (size_t)e * R * C;
    unsigned short* dst = out + (size_t)e * R * C;
    int r0 = blockIdx.x * 64, c0 = blockIdx.y * 64;
    int tid = threadIdx.x;
    int rr = tid >> 2, cb = (tid & 3) * 16;
#pragma unroll
    for (int i = 0; i < 4; ++i) {
        float4 v = *(const float4*)&src[(size_t)(r0 + rr) * C + c0 + cb + i * 4];
        tile[rr][cb + i * 4 + 0] = f2bf(v.x);
        tile[rr][cb + i * 4 + 1] = f2bf(v.y);
        tile[rr][cb + i * 4 + 2] = f2bf(v.z);
        tile[rr][cb + i * 4 + 3] = f2bf(v.w);
    }
    __syncthreads();
#pragma unroll
    for (int i = 0; i < 4; ++i) {
        ushort4 u;
        u.x = tile[cb + i * 4 + 0][rr];
        u.y = tile[cb + i * 4 + 1][rr];
        u.z = tile[cb + i * 4 + 2][rr];
        u.w = tile[cb + i * 4 + 3][rr];
        *(ushort4*)&dst[(size_t)(c0 + rr) * R + r0 + cb + i * 4] = u;
    }
}

// ------------------------------------------------------------- MFMA GEMM ----
// LDS tiles: 128 rows x 32 bf16, unpadded 64-B rows (global_load_lds dest is
// lane-linear). gemm1: A=W1t (m=h) -> packed ushort4 H1 stores. gemm2:
// A=H1 (m=slot), B=W2t (n=d) -> full-line coalesced atomics.

__global__ __launch_bounds__(256) void gemm1_kernel(
    const unsigned short* __restrict__ Xb, const unsigned short* __restrict__ W1t,
    const float* __restrict__ b1, const int* __restrict__ cnt,
    const int* __restrict__ offs, const int* __restrict__ btok,
    const unsigned short* __restrict__ tile_tab, const int* __restrict__ ntile,
    unsigned short* __restrict__ H1)
{
    __shared__ __align__(16) unsigned short Ws[128 * 32];  // W1t rows (h)
    __shared__ __align__(16) unsigned short Xs[128 * 32];  // X rows (tokens)
    __shared__ int tok_s[128];

    int ti = blockIdx.x;
    if (ti >= *ntile) return;
    unsigned short tv = tile_tab[ti];
    int e = tv >> 8, tt = tv & 255, ht = blockIdx.y;
    int cn = cnt[e];
    int off_e = offs[e];
    int tid = threadIdx.x;

    if (tid < 128) {
        int lr = tt * 128 + tid;
        tok_s[tid] = (lr < cn) ? btok[off_e + lr] : 0;
    }
    __syncthreads();

    int wave = tid >> 6, lane = tid & 63;
    int mbase = (wave >> 1) * 64, nbase = (wave & 1) * 64;
    f32x4 acc[4][4];
#pragma unroll
    for (int mi = 0; mi < 4; ++mi)
#pragma unroll
        for (int ni = 0; ni < 4; ++ni)
            acc[mi][ni] = (f32x4){0.f, 0.f, 0.f, 0.f};

    int R0 = tid >> 2, cb = (tid & 3) * 8;
    const unsigned short* Wsrc = W1t + ((size_t)e * HID + ht * 128) * DIM;
    int ka = (lane >> 4) * 8;
    int lcol = lane & 15;

    for (int k0 = 0; k0 < DIM; k0 += 32) {
#pragma unroll
        for (int p = 0; p < 2; ++p) {
            int R = R0 + p * 64;
            load16_to_lds(&Wsrc[(size_t)R * DIM + k0 + cb], &Ws[R * 32 + cb]);
            load16_to_lds(&Xb[(size_t)tok_s[R] * DIM + k0 + cb], &Xs[R * 32 + cb]);
        }
        __syncthreads();
        short8 a[4], b[4];
#pragma unroll
        for (int i = 0; i < 4; ++i) {
            a[i] = *(const short8*)&Ws[(mbase + i * 16 + lcol) * 32 + ka];
            b[i] = *(const short8*)&Xs[(nbase + i * 16 + lcol) * 32 + ka];
        }
#pragma unroll
        for (int mi = 0; mi < 4; ++mi)
#pragma unroll
            for (int ni = 0; ni < 4; ++ni)
                acc[mi][ni] = __builtin_amdgcn_mfma_f32_16x16x32_bf16(
                    a[mi], b[ni], acc[mi][ni], 0, 0, 0);
        __syncthreads();
    }

    int quad = lane >> 4;
    float4 bv[4];
#pragma unroll
    for (int mi = 0; mi < 4; ++mi)
        bv[mi] = *(const float4*)&b1[e * HID + ht * 128 + mbase + mi * 16 + quad * 4];
#pragma unroll
    for (int ni = 0; ni < 4; ++ni) {
        int tn = tt * 128 + nbase + ni * 16 + lcol;
        if (tn >= cn) continue;
        size_t srow = (size_t)(off_e + tn) * HID + ht * 128;
#pragma unroll
        for (int mi = 0; mi < 4; ++mi) {
            int h = mbase + mi * 16 + quad * 4;
            ushort4 u;
            u.x = f2bf(acc[mi][ni][0] + bv[mi].x);
            u.y = f2bf(acc[mi][ni][1] + bv[mi].y);
            u.z = f2bf(acc[mi][ni][2] + bv[mi].z);
            u.w = f2bf(acc[mi][ni][3] + bv[mi].w);
            *(ushort4*)&H1[srow + h] = u;
        }
    }
}

#define KSPLIT 2
#define KCH (HID / KSPLIT)

__global__ __launch_bounds__(256) void gemm2_kernel(
    const unsigned short* __restrict__ H1, const unsigned short* __restrict__ W2t,
    const float* __restrict__ b2, const int* __restrict__ cnt,
    const int* __restrict__ offs, const int* __restrict__ btok,
    const float* __restrict__ bwt,
    const unsigned short* __restrict__ tile_tab, const int* __restrict__ ntile,
    float* __restrict__ out)
{
    __shared__ __align__(16) unsigned short Ws[128 * 32];  // W2t rows (d)
    __shared__ __align__(16) unsigned short Hs[128 * 32];  // H1 rows (slots)
    __shared__ int   tok_s[128];
    __shared__ float wt_s[128];

    int ti = blockIdx.x;
    if (ti >= *ntile) return;
    unsigned short tv = tile_tab[ti];
    int e = tv >> 8, tt = tv & 255, dt = blockIdx.y, kz = blockIdx.z;
    int cn = cnt[e];
    int off_e = offs[e];
    int sb = off_e + tt * 128;
    int tid = threadIdx.x;

    if (tid < 128) {
        int lr = tt * 128 + tid;
        if (lr < cn) { tok_s[tid] = btok[off_e + lr]; wt_s[tid] = bwt[off_e + lr]; }
        else         { tok_s[tid] = 0;               wt_s[tid] = 0.f; }
    }
    __syncthreads();

    int wave = tid >> 6, lane = tid & 63;
    int mbase = (wave >> 1) * 64, nbase = (wave & 1) * 64;   // m=slot, n=d
    f32x4 acc[4][4];
#pragma unroll
    for (int mi = 0; mi < 4; ++mi)
#pragma unroll
        for (int ni = 0; ni < 4; ++ni)
            acc[mi][ni] = (f32x4){0.f, 0.f, 0.f, 0.f};

    int R0 = tid >> 2, cb = (tid & 3) * 8;
    const unsigned short* Wsrc = W2t + ((size_t)e * DIM + dt * 128) * HID;
    int ka = (lane >> 4) * 8;
    int lcol = lane & 15;

    for (int k0 = kz * KCH; k0 < (kz + 1) * KCH; k0 += 32) {
#pragma unroll
        for (int p = 0; p < 2; ++p) {
            int R = R0 + p * 64;
            int sr = sb + R; if (sr > TOTSLOT - 1) sr = TOTSLOT - 1;
            load16_to_lds(&Wsrc[(size_t)R * HID + k0 + cb], &Ws[R * 32 + cb]);
            load16_to_lds(&H1[(size_t)sr * HID + k0 + cb], &Hs[R * 32 + cb]);
        }
        __syncthreads();
        short8 a[4], b[4];
#pragma unroll
        for (int i = 0; i < 4; ++i) {
            a[i] = *(const short8*)&Hs[(mbase + i * 16 + lcol) * 32 + ka];  // A = slots
            b[i] = *(const short8*)&Ws[(nbase + i * 16 + lcol) * 32 + ka];  // B = d
        }
#pragma unroll
        for (int mi = 0; mi < 4; ++mi)
#pragma unroll
            for (int ni = 0; ni < 4; ++ni)
                acc[mi][ni] = __builtin_amdgcn_mfma_f32_16x16x32_bf16(
                    a[mi], b[ni], acc[mi][ni], 0, 0, 0);
        __syncthreads();
    }

    // Epilogue (round-4 geometry): per instruction, 16 lanes write 16
    // consecutive d of one slot-row -> full 64-B line atomics.
    int quad = lane >> 4;
#pragma unroll
    for (int ni = 0; ni < 4; ++ni) {
        int d = dt * 128 + nbase + ni * 16 + lcol;
        float bv = (kz == 0) ? b2[e * DIM + d] : 0.f;
#pragma unroll
        for (int mi = 0; mi < 4; ++mi) {
            int rl = mbase + mi * 16 + quad * 4;
#pragma unroll
            for (int r = 0; r < 4; ++r) {
                int sl = rl + r;
                if (tt * 128 + sl < cn) {
                    float w = wt_s[sl];
                    atomicAdd(&out[(size_t)tok_s[sl] * DIM + d],
                              w * (acc[mi][ni][r] + bv));
                }
            }
        }
    }
}

// ------------------------------------------------- round-1 fp32 fallback ----
#define TN 16
#define HC 256
#define NCHUNK (HID / HC)

__global__ __launch_bounds__(256) void gating_fb_kernel(
    const float* __restrict__ x, const float* __restrict__ Wg,
    const float* __restrict__ bg,
    int* __restrict__ cnt, int* __restrict__ btok, float* __restrict__ bwt,
    float* __restrict__ usage)
{
    int wave = threadIdx.x >> 6;
    int lane = threadIdx.x & 63;
    int n = blockIdx.x * 4 + wave;
    float acc[NEXP];
#pragma unroll
    for (int e = 0; e < NEXP; ++e) acc[e] = 0.f;
    for (int d = lane; d < DIM; d += 64) {
        float xv = x[n * DIM + d];
        float4 wa = *(const float4*)&Wg[d * NEXP];
        float4 wb = *(const float4*)&Wg[d * NEXP + 4];
        acc[0] += xv * wa.x; acc[1] += xv * wa.y;
        acc[2] += xv * wa.z; acc[3] += xv * wa.w;
        acc[4] += xv * wb.x; acc[5] += xv * wb.y;
        acc[6] += xv * wb.z; acc[7] += xv * wb.w;
    }
#pragma unroll
    for (int m = 32; m >= 1; m >>= 1)
#pragma unroll
        for (int e = 0; e < NEXP; ++e)
            acc[e] += __shfl_xor(acc[e], m, 64);
    if (lane == 0) {
        float l[NEXP];
#pragma unroll
        for (int e = 0; e < NEXP; ++e) l[e] = acc[e] + bg[e];
        int i0 = 0;
#pragma unroll
        for (int e = 1; e < NEXP; ++e) if (l[e] > l[i0]) i0 = e;
        int i1 = (i0 == 0) ? 1 : 0;
#pragma unroll
        for (int e = 0; e < NEXP; ++e)
            if (e != i0 && l[e] > l[i1]) i1 = e;
        float w0 = 1.f / (1.f + expf(l[i1] - l[i0]));
        float w1 = 1.f - w0;
        int p0 = atomicAdd(&cnt[i0], 1);
        btok[i0 * N_TOK + p0] = n; bwt[i0 * N_TOK + p0] = w0;
        int p1 = atomicAdd(&cnt[i1], 1);
        btok[i1 * N_TOK + p1] = n; bwt[i1 * N_TOK + p1] = w1;
        atomicAdd(&usage[i0], w0);
        atomicAdd(&usage[i1], w1);
    }
}

__global__ __launch_bounds__(256) void expert_fb_kernel(
    const float* __restrict__ x, const float* __restrict__ W1,
    const float* __restrict__ b1, const float* __restrict__ W2,
    const float* __restrict__ b2, const int* __restrict__ cnt,
    const int* __restrict__ btok, const float* __restrict__ bwt,
    float* __restrict__ out)
{
    __shared__ float xs[TN][DIM];
    __shared__ float h1s[TN][HC];
    __shared__ int   tok_s[TN];
    __shared__ float wt_s[TN];
    int e = blockIdx.x >> 8;
    int tile = blockIdx.x & 255;
    int cn = cnt[e];
    int n0 = tile * TN;
    if (n0 >= cn) return;
    int nt = min(TN, cn - n0);
    int tid = threadIdx.x;
    if (tid < TN) {
        if (tid < nt) { tok_s[tid] = btok[e * N_TOK + n0 + tid]; wt_s[tid] = bwt[e * N_TOK + n0 + tid]; }
        else          { tok_s[tid] = 0; wt_s[tid] = 0.f; }
    }
    __syncthreads();
    for (int idx = tid; idx < TN * DIM; idx += 256) {
        int t = idx >> 9, d = idx & 511;
        xs[t][d] = (t < nt) ? x[tok_s[t] * DIM + d] : 0.f;
    }
    const float* W1e = W1 + (size_t)e * DIM * HID;
    const float* W2e = W2 + (size_t)e * HID * DIM;
    int tg = tid >> 6, lane = tid & 63;
    float oacc[4][8];
    {
        float4 ba = *(const float4*)&b2[e * DIM + lane * 8];
        float4 bb = *(const float4*)&b2[e * DIM + lane * 8 + 4];
#pragma unroll
        for (int ti = 0; ti < 4; ++ti) {
            oacc[ti][0] = ba.x; oacc[ti][1] = ba.y; oacc[ti][2] = ba.z; oacc[ti][3] = ba.w;
            oacc[ti][4] = bb.x; oacc[ti][5] = bb.y; oacc[ti][6] = bb.z; oacc[ti][7] = bb.w;
        }
    }
    __syncthreads();
    for (int ch = 0; ch < NCHUNK; ++ch) {
        int h0 = ch * HC;
        float f[4][4];
        {
            float4 b1v = *(const float4*)&b1[e * HID + h0 + lane * 4];
#pragma unroll
            for (int ti = 0; ti < 4; ++ti) {
                f[ti][0] = b1v.x; f[ti][1] = b1v.y; f[ti][2] = b1v.z; f[ti][3] = b1v.w;
            }
        }
        for (int d = 0; d < DIM; ++d) {
            float4 w1v = *(const float4*)&W1e[(size_t)d * HID + h0 + lane * 4];
#pragma unroll
            for (int ti = 0; ti < 4; ++ti) {
                float xv = xs[tg + 4 * ti][d];
                f[ti][0] += xv * w1v.x; f[ti][1] += xv * w1v.y;
                f[ti][2] += xv * w1v.z; f[ti][3] += xv * w1v.w;
            }
        }
        __syncthreads();
#pragma unroll
        for (int ti = 0; ti < 4; ++ti)
            *(float4*)&h1s[tg + 4 * ti][lane * 4] = make_float4(f[ti][0], f[ti][1], f[ti][2], f[ti][3]);
        __syncthreads();
        for (int j = 0; j < HC; ++j) {
            const float* w2row = &W2e[(size_t)(h0 + j) * DIM + lane * 8];
            float4 wa = *(const float4*)w2row;
            float4 wb = *(const float4*)(w2row + 4);
#pragma unroll
            for (int ti = 0; ti < 4; ++ti) {
                float hv = h1s[tg + 4 * ti][j];
                oacc[ti][0] += hv * wa.x; oacc[ti][1] += hv * wa.y;
                oacc[ti][2] += hv * wa.z; oacc[ti][3] += hv * wa.w;
                oacc[ti][4] += hv * wb.x; oacc[ti][5] += hv * wb.y;
                oacc[ti][6] += hv * wb.z; oacc[ti][7] += hv * wb.w;
            }
        }
    }
#pragma unroll
    for (int ti = 0; ti < 4; ++ti) {
        int t = tg + 4 * ti;
        if (t < nt) {
            float w = wt_s[t];
            float* o = &out[(size_t)tok_s[t] * DIM + lane * 8];
#pragma unroll
            for (int c = 0; c < 8; ++c)
                atomicAdd(&o[c], w * oacc[ti][c]);
        }
    }
}

// ------------------------------------------------------------------ host ----
extern "C" void kernel_launch(void* const* d_in, const int* in_sizes, int n_in,
                              void* d_out, int out_size, void* d_ws, size_t ws_size,
                              hipStream_t stream) {
    const float* x  = (const float*)d_in[0];
    const float* Wg = (const float*)d_in[1];
    const float* bg = (const float*)d_in[2];
    const float* W1 = (const float*)d_in[3];
    const float* b1 = (const float*)d_in[4];
    const float* W2 = (const float*)d_in[5];
    const float* b2 = (const float*)d_in[6];

    float* out   = (float*)d_out;
    float* usage = out + (size_t)N_TOK * DIM;

    // ws layout (bf16 path)
    char* ws = (char*)d_ws;
    int*   cnt  = (int*)(ws + 0);
    int*   fill = (int*)(ws + 32);
    int*   offs = (int*)(ws + 64);
    unsigned short* tile_tab = (unsigned short*)(ws + 96);
    int*   ntile = (int*)(ws + 240);
    int*   te   = (int*)(ws + 256);
    float* tw   = (float*)(ws + 33024);
    int*   btok = (int*)(ws + 65792);
    float* bwt  = (float*)(ws + 98560);
    unsigned short* Xb  = (unsigned short*)(ws + 131328);
    unsigned short* W1t = (unsigned short*)(ws + 4325632);
    unsigned short* W2t = (unsigned short*)(ws + 21102848);
    unsigned short* H1  = (unsigned short*)(ws + 37880064);
    const size_t WS_NEED = 71434496ULL;

    hipMemsetAsync(d_out, 0, (size_t)(N_TOK * DIM + NEXP) * sizeof(float), stream);

    if (ws_size >= WS_NEED) {
        hipMemsetAsync(cnt, 0, 32, stream);
        cvtx_kernel<<<N_TOK * DIM / 1024, 256, 0, stream>>>(x, Xb);
        transpose_cvt_kernel<<<dim3(DIM / 64, HID / 64, NEXP), 256, 0, stream>>>(W1, W1t, DIM, HID);
        transpose_cvt_kernel<<<dim3(HID / 64, DIM / 64, NEXP), 256, 0, stream>>>(W2, W2t, HID, DIM);
        gating_kernel<<<N_TOK / 64, 256, 0, stream>>>(x, Wg, bg, cnt, te, tw, usage);
        prefix_kernel<<<1, 64, 0, stream>>>(cnt, offs, fill, tile_tab, ntile);
        scatter_kernel<<<N_TOK / 256, 256, 0, stream>>>(te, tw, offs, fill, btok, bwt);
        gemm1_kernel<<<dim3(MAXTILE, HID / 128), 256, 0, stream>>>(
            Xb, W1t, b1, cnt, offs, btok, tile_tab, ntile, H1);
        gemm2_kernel<<<dim3(MAXTILE, DIM / 128, KSPLIT), 256, 0, stream>>>(
            H1, W2t, b2, cnt, offs, btok, bwt, tile_tab, ntile, out);
    } else {
        // round-1 fp32 fallback (verified)
        int*   fcnt  = (int*)d_ws;
        int*   fbtok = (int*)((char*)d_ws + 256);
        float* fbwt  = (float*)((char*)d_ws + 256 + (size_t)NEXP * N_TOK * sizeof(int));
        hipMemsetAsync(d_ws, 0, 256, stream);
        gating_fb_kernel<<<N_TOK / 4, 256, 0, stream>>>(x, Wg, bg, fcnt, fbtok, fbwt, usage);
        expert_fb_kernel<<<NEXP * (N_TOK / TN), 256, 0, stream>>>(
            x, W1, b1, W2, b2, fcnt, fbtok, fbwt, out);
    }
}

// Round 7
// 271.093 us; speedup vs baseline: 1.3132x; 1.0383x over previous
//
#include <hip/hip_runtime.h>
#include <hip/hip_bf16.h>

// MoE: N=4096 tokens, D=512, H=2048, E=8 experts, top-2.
// Round 7: (1) BK=64 K-loop with XOR-swizzled LDS (chunk c of row R stored at
// physical c^(R&7); staging swizzles the GLOBAL address so global_load_lds
// stays lane-linear; fragment b128 reads spread over all 32 banks -> 2-way =
// free, was 8-way ~+8.5cyc). Halves barriers, 32 MFMA/barrier. (2) gemm2
// KSPLIT=4: live blocks 512->1024 (~4/CU) to hide barrier drain; atomic
// payload doubles 33.5->67MB (accepted). (3) gating 256 blocks (was 64 = 25%
// of CUs). Epilogues/plumbing unchanged from verified round 6.

#define N_TOK 4096
#define DIM   512
#define HID   2048
#define NEXP  8
#define TOTSLOT (2 * N_TOK)
#define MAXTILE 72

typedef __attribute__((ext_vector_type(8))) short short8;
typedef __attribute__((ext_vector_type(4))) float f32x4;

static __device__ __forceinline__ unsigned short f2bf(float f) {
    __hip_bfloat16 b = __float2bfloat16(f);
    return *reinterpret_cast<unsigned short*>(&b);
}

static __device__ __forceinline__ void load16_to_lds(const void* g, void* l) {
    __builtin_amdgcn_global_load_lds(
        (const __attribute__((address_space(1))) unsigned int*)g,
        (__attribute__((address_space(3))) unsigned int*)l, 16, 0, 0);
}

// ---------------------------------------------------------------- gating ----
// 256 blocks x 16 tokens; wave w handles tokens [w*4, w*4+4).
__global__ __launch_bounds__(256) void gating_kernel(
    const float* __restrict__ x, const float* __restrict__ Wg,
    const float* __restrict__ bg,
    int* __restrict__ cnt, int* __restrict__ te, float* __restrict__ tw,
    float* __restrict__ usage)
{
    __shared__ int   lcnt[NEXP];
    __shared__ float lus[NEXP];
    int tid = threadIdx.x;
    if (tid < NEXP) { lcnt[tid] = 0; lus[tid] = 0.f; }
    __syncthreads();

    int wave = tid >> 6;
    int lane = tid & 63;

    for (int t = 0; t < 4; ++t) {
        int n = blockIdx.x * 16 + wave * 4 + t;

        float acc[NEXP];
#pragma unroll
        for (int e = 0; e < NEXP; ++e) acc[e] = 0.f;

#pragma unroll
        for (int it = 0; it < DIM / 64; ++it) {
            int d = it * 64 + lane;
            float xv = x[n * DIM + d];
            float4 wa = *(const float4*)&Wg[d * NEXP];
            float4 wb = *(const float4*)&Wg[d * NEXP + 4];
            acc[0] += xv * wa.x; acc[1] += xv * wa.y;
            acc[2] += xv * wa.z; acc[3] += xv * wa.w;
            acc[4] += xv * wb.x; acc[5] += xv * wb.y;
            acc[6] += xv * wb.z; acc[7] += xv * wb.w;
        }
#pragma unroll
        for (int m = 32; m >= 1; m >>= 1) {
#pragma unroll
            for (int e = 0; e < NEXP; ++e)
                acc[e] += __shfl_xor(acc[e], m, 64);
        }
        if (lane == 0) {
            float l[NEXP];
#pragma unroll
            for (int e = 0; e < NEXP; ++e) l[e] = acc[e] + bg[e];
            int i0 = 0;
#pragma unroll
            for (int e = 1; e < NEXP; ++e) if (l[e] > l[i0]) i0 = e;
            int i1 = (i0 == 0) ? 1 : 0;
#pragma unroll
            for (int e = 0; e < NEXP; ++e)
                if (e != i0 && l[e] > l[i1]) i1 = e;
            float w0 = 1.f / (1.f + expf(l[i1] - l[i0]));
            float w1 = 1.f - w0;
            te[n * 2] = i0; te[n * 2 + 1] = i1;
            tw[n * 2] = w0; tw[n * 2 + 1] = w1;
            atomicAdd(&lcnt[i0], 1);
            atomicAdd(&lcnt[i1], 1);
            atomicAdd(&lus[i0], w0);
            atomicAdd(&lus[i1], w1);
        }
    }
    __syncthreads();
    if (tid < NEXP) {
        if (lcnt[tid]) atomicAdd(&cnt[tid], lcnt[tid]);
        if (lus[tid] != 0.f) atomicAdd(&usage[tid], lus[tid]);
    }
}

__global__ void prefix_kernel(const int* __restrict__ cnt,
                              int* __restrict__ offs, int* __restrict__ fill,
                              unsigned short* __restrict__ tile_tab,
                              int* __restrict__ ntile)
{
    if (threadIdx.x == 0) {
        int s = 0, nt = 0;
        for (int e = 0; e < NEXP; ++e) {
            offs[e] = s; s += cnt[e];
            int t = (cnt[e] + 127) >> 7;
            for (int i = 0; i < t; ++i)
                tile_tab[nt++] = (unsigned short)((e << 8) | i);
        }
        *ntile = nt;
        for (int i = nt; i < MAXTILE; ++i) tile_tab[i] = 0;
    }
    if (threadIdx.x < NEXP) fill[threadIdx.x] = 0;
}

__global__ __launch_bounds__(256) void scatter_kernel(
    const int* __restrict__ te, const float* __restrict__ tw,
    const int* __restrict__ offs, int* __restrict__ fill,
    int* __restrict__ btok, float* __restrict__ bwt)
{
    __shared__ int lcnt[NEXP];
    __shared__ int gbase[NEXP];
    int tid = threadIdx.x;
    if (tid < NEXP) lcnt[tid] = 0;
    __syncthreads();
    int n = blockIdx.x * 256 + tid;
    int e0 = te[n * 2], e1 = te[n * 2 + 1];
    int l0 = atomicAdd(&lcnt[e0], 1);
    int l1 = atomicAdd(&lcnt[e1], 1);
    __syncthreads();
    if (tid < NEXP) gbase[tid] = atomicAdd(&fill[tid], lcnt[tid]);
    __syncthreads();
    int s0 = offs[e0] + gbase[e0] + l0;
    int s1 = offs[e1] + gbase[e1] + l1;
    btok[s0] = n; bwt[s0] = tw[n * 2];
    btok[s1] = n; bwt[s1] = tw[n * 2 + 1];
}

// ----------------------------------------------------------- conversions ----
__global__ __launch_bounds__(256) void cvtx_kernel(
    const float* __restrict__ x, unsigned short* __restrict__ Xb)
{
    int i = (blockIdx.x * 256 + threadIdx.x) * 4;
    float4 v = *(const float4*)&x[i];
    ushort4 u;
    u.x = f2bf(v.x); u.y = f2bf(v.y); u.z = f2bf(v.z); u.w = f2bf(v.w);
    *(ushort4*)&Xb[i] = u;
}

// in: [E][R][C] fp32  ->  out: [E][C][R] bf16
__global__ __launch_bounds__(256) void transpose_cvt_kernel(
    const float* __restrict__ in, unsigned short* __restrict__ out,
    int R, int C)
{
    __shared__ unsigned short tile[64][65];
    int e = blockIdx.z;
    const float* src = in + (size_t)e * R * C;
    unsigned short* dst = out + (size_t)e * R * C;
    int r0 = blockIdx.x * 64, c0 = blockIdx.y * 64;
    int tid = threadIdx.x;
    int rr = tid >> 2, cb = (tid & 3) * 16;
#pragma unroll
    for (int i = 0; i < 4; ++i) {
        float4 v = *(const float4*)&src[(size_t)(r0 + rr) * C + c0 + cb + i * 4];
        tile[rr][cb + i * 4 + 0] = f2bf(v.x);
        tile[rr][cb + i * 4 + 1] = f2bf(v.y);
        tile[rr][cb + i * 4 + 2] = f2bf(v.z);
        tile[rr][cb + i * 4 + 3] = f2bf(v.w);
    }
    __syncthreads();
#pragma unroll
    for (int i = 0; i < 4; ++i) {
        ushort4 u;
        u.x = tile[cb + i * 4 + 0][rr];
        u.y = tile[cb + i * 4 + 1][rr];
        u.z = tile[cb + i * 4 + 2][rr];
        u.w = tile[cb + i * 4 + 3][rr];
        *(ushort4*)&dst[(size_t)(c0 + rr) * R + r0 + cb + i * 4] = u;
    }
}

// ------------------------------------------------------------- MFMA GEMM ----
// LDS: 128 rows x 64 bf16 (128-B rows), 8x 16-B chunks/row, chunk c of row R
// at physical slot c^(R&7). Staging: lane owns physical slot (tid&7), loads
// global chunk (tid&7)^(R&7) -> lane-linear LDS dest. Fragment read for
// logical chunk cl (=half*4+quad) of row m: physical (cl^(m&7)) -> 16 lcol
// lanes spread over 8 bank-windows (2-way = free).

__global__ __launch_bounds__(256) void gemm1_kernel(
    const unsigned short* __restrict__ Xb, const unsigned short* __restrict__ W1t,
    const float* __restrict__ b1, const int* __restrict__ cnt,
    const int* __restrict__ offs, const int* __restrict__ btok,
    const unsigned short* __restrict__ tile_tab, const int* __restrict__ ntile,
    unsigned short* __restrict__ H1)
{
    __shared__ __align__(16) unsigned short Ws[128 * 64];  // W1t rows (h)
    __shared__ __align__(16) unsigned short Xs[128 * 64];  // X rows (tokens)
    __shared__ int tok_s[128];

    int ti = blockIdx.x;
    if (ti >= *ntile) return;
    unsigned short tv = tile_tab[ti];
    int e = tv >> 8, tt = tv & 255, ht = blockIdx.y;
    int cn = cnt[e];
    int off_e = offs[e];
    int tid = threadIdx.x;

    if (tid < 128) {
        int lr = tt * 128 + tid;
        tok_s[tid] = (lr < cn) ? btok[off_e + lr] : 0;
    }
    __syncthreads();

    int wave = tid >> 6, lane = tid & 63;
    int mbase = (wave >> 1) * 64, nbase = (wave & 1) * 64;
    int quad = lane >> 4, lcol = lane & 15;
    f32x4 acc[4][4];
#pragma unroll
    for (int mi = 0; mi < 4; ++mi)
#pragma unroll
        for (int ni = 0; ni < 4; ++ni)
            acc[mi][ni] = (f32x4){0.f, 0.f, 0.f, 0.f};

    int Rb = tid >> 3, pc = tid & 7;
    const unsigned short* Wsrc = W1t + ((size_t)e * HID + ht * 128) * DIM;

    for (int k0 = 0; k0 < DIM; k0 += 64) {
#pragma unroll
        for (int p = 0; p < 4; ++p) {
            int R = Rb + p * 32;
            int c = pc ^ (R & 7);
            load16_to_lds(&Wsrc[(size_t)R * DIM + k0 + c * 8], &Ws[R * 64 + pc * 8]);
            load16_to_lds(&Xb[(size_t)tok_s[R] * DIM + k0 + c * 8], &Xs[R * 64 + pc * 8]);
        }
        __syncthreads();
#pragma unroll
        for (int h = 0; h < 2; ++h) {
            int cs = ((h * 4 + quad) ^ (lcol & 7)) * 8;
            short8 a[4], b[4];
#pragma unroll
            for (int i = 0; i < 4; ++i) {
                a[i] = *(const short8*)&Ws[(mbase + i * 16 + lcol) * 64 + cs];
                b[i] = *(const short8*)&Xs[(nbase + i * 16 + lcol) * 64 + cs];
            }
#pragma unroll
            for (int mi = 0; mi < 4; ++mi)
#pragma unroll
                for (int ni = 0; ni < 4; ++ni)
                    acc[mi][ni] = __builtin_amdgcn_mfma_f32_16x16x32_bf16(
                        a[mi], b[ni], acc[mi][ni], 0, 0, 0);
        }
        __syncthreads();
    }

    float4 bv[4];
#pragma unroll
    for (int mi = 0; mi < 4; ++mi)
        bv[mi] = *(const float4*)&b1[e * HID + ht * 128 + mbase + mi * 16 + quad * 4];
#pragma unroll
    for (int ni = 0; ni < 4; ++ni) {
        int tn = tt * 128 + nbase + ni * 16 + lcol;
        if (tn >= cn) continue;
        size_t srow = (size_t)(off_e + tn) * HID + ht * 128;
#pragma unroll
        for (int mi = 0; mi < 4; ++mi) {
            int hh = mbase + mi * 16 + quad * 4;
            ushort4 u;
            u.x = f2bf(acc[mi][ni][0] + bv[mi].x);
            u.y = f2bf(acc[mi][ni][1] + bv[mi].y);
            u.z = f2bf(acc[mi][ni][2] + bv[mi].z);
            u.w = f2bf(acc[mi][ni][3] + bv[mi].w);
            *(ushort4*)&H1[srow + hh] = u;
        }
    }
}

#define KSPLIT 4
#define KCH (HID / KSPLIT)

__global__ __launch_bounds__(256) void gemm2_kernel(
    const unsigned short* __restrict__ H1, const unsigned short* __restrict__ W2t,
    const float* __restrict__ b2, const int* __restrict__ cnt,
    const int* __restrict__ offs, const int* __restrict__ btok,
    const float* __restrict__ bwt,
    const unsigned short* __restrict__ tile_tab, const int* __restrict__ ntile,
    float* __restrict__ out)
{
    __shared__ __align__(16) unsigned short Ws[128 * 64];  // W2t rows (d)
    __shared__ __align__(16) unsigned short Hs[128 * 64];  // H1 rows (slots)
    __shared__ int   tok_s[128];
    __shared__ float wt_s[128];

    int ti = blockIdx.x;
    if (ti >= *ntile) return;
    unsigned short tv = tile_tab[ti];
    int e = tv >> 8, tt = tv & 255, dt = blockIdx.y, kz = blockIdx.z;
    int cn = cnt[e];
    int off_e = offs[e];
    int sb = off_e + tt * 128;
    int tid = threadIdx.x;

    if (tid < 128) {
        int lr = tt * 128 + tid;
        if (lr < cn) { tok_s[tid] = btok[off_e + lr]; wt_s[tid] = bwt[off_e + lr]; }
        else         { tok_s[tid] = 0;               wt_s[tid] = 0.f; }
    }
    __syncthreads();

    int wave = tid >> 6, lane = tid & 63;
    int mbase = (wave >> 1) * 64, nbase = (wave & 1) * 64;   // m=slot, n=d
    int quad = lane >> 4, lcol = lane & 15;
    f32x4 acc[4][4];
#pragma unroll
    for (int mi = 0; mi < 4; ++mi)
#pragma unroll
        for (int ni = 0; ni < 4; ++ni)
            acc[mi][ni] = (f32x4){0.f, 0.f, 0.f, 0.f};

    int Rb = tid >> 3, pc = tid & 7;
    const unsigned short* Wsrc = W2t + ((size_t)e * DIM + dt * 128) * HID;

    for (int k0 = kz * KCH; k0 < (kz + 1) * KCH; k0 += 64) {
#pragma unroll
        for (int p = 0; p < 4; ++p) {
            int R = Rb + p * 32;
            int c = pc ^ (R & 7);
            int sr = sb + R; if (sr > TOTSLOT - 1) sr = TOTSLOT - 1;
            load16_to_lds(&Wsrc[(size_t)R * HID + k0 + c * 8], &Ws[R * 64 + pc * 8]);
            load16_to_lds(&H1[(size_t)sr * HID + k0 + c * 8], &Hs[R * 64 + pc * 8]);
        }
        __syncthreads();
#pragma unroll
        for (int h = 0; h < 2; ++h) {
            int cs = ((h * 4 + quad) ^ (lcol & 7)) * 8;
            short8 a[4], b[4];
#pragma unroll
            for (int i = 0; i < 4; ++i) {
                a[i] = *(const short8*)&Hs[(mbase + i * 16 + lcol) * 64 + cs];  // A = slots
                b[i] = *(const short8*)&Ws[(nbase + i * 16 + lcol) * 64 + cs];  // B = d
            }
#pragma unroll
            for (int mi = 0; mi < 4; ++mi)
#pragma unroll
                for (int ni = 0; ni < 4; ++ni)
                    acc[mi][ni] = __builtin_amdgcn_mfma_f32_16x16x32_bf16(
                        a[mi], b[ni], acc[mi][ni], 0, 0, 0);
        }
        __syncthreads();
    }

    // Epilogue: 16 lcol lanes write 16 consecutive d of one slot-row ->
    // full 64-B line atomics (verified geometry, rounds 4/6).
#pragma unroll
    for (int ni = 0; ni < 4; ++ni) {
        int d = dt * 128 + nbase + ni * 16 + lcol;
        float bv = (kz == 0) ? b2[e * DIM + d] : 0.f;
#pragma unroll
        for (int mi = 0; mi < 4; ++mi) {
            int rl = mbase + mi * 16 + quad * 4;
#pragma unroll
            for (int r = 0; r < 4; ++r) {
                int sl = rl + r;
                if (tt * 128 + sl < cn) {
                    float w = wt_s[sl];
                    atomicAdd(&out[(size_t)tok_s[sl] * DIM + d],
                              w * (acc[mi][ni][r] + bv));
                }
            }
        }
    }
}

// ------------------------------------------------- round-1 fp32 fallback ----
#define TN 16
#define HC 256
#define NCHUNK (HID / HC)

__global__ __launch_bounds__(256) void gating_fb_kernel(
    const float* __restrict__ x, const float* __restrict__ Wg,
    const float* __restrict__ bg,
    int* __restrict__ cnt, int* __restrict__ btok, float* __restrict__ bwt,
    float* __restrict__ usage)
{
    int wave = threadIdx.x >> 6;
    int lane = threadIdx.x & 63;
    int n = blockIdx.x * 4 + wave;
    float acc[NEXP];
#pragma unroll
    for (int e = 0; e < NEXP; ++e) acc[e] = 0.f;
    for (int d = lane; d < DIM; d += 64) {
        float xv = x[n * DIM + d];
        float4 wa = *(const float4*)&Wg[d * NEXP];
        float4 wb = *(const float4*)&Wg[d * NEXP + 4];
        acc[0] += xv * wa.x; acc[1] += xv * wa.y;
        acc[2] += xv * wa.z; acc[3] += xv * wa.w;
        acc[4] += xv * wb.x; acc[5] += xv * wb.y;
        acc[6] += xv * wb.z; acc[7] += xv * wb.w;
    }
#pragma unroll
    for (int m = 32; m >= 1; m >>= 1)
#pragma unroll
        for (int e = 0; e < NEXP; ++e)
            acc[e] += __shfl_xor(acc[e], m, 64);
    if (lane == 0) {
        float l[NEXP];
#pragma unroll
        for (int e = 0; e < NEXP; ++e) l[e] = acc[e] + bg[e];
        int i0 = 0;
#pragma unroll
        for (int e = 1; e < NEXP; ++e) if (l[e] > l[i0]) i0 = e;
        int i1 = (i0 == 0) ? 1 : 0;
#pragma unroll
        for (int e = 0; e < NEXP; ++e)
            if (e != i0 && l[e] > l[i1]) i1 = e;
        float w0 = 1.f / (1.f + expf(l[i1] - l[i0]));
        float w1 = 1.f - w0;
        int p0 = atomicAdd(&cnt[i0], 1);
        btok[i0 * N_TOK + p0] = n; bwt[i0 * N_TOK + p0] = w0;
        int p1 = atomicAdd(&cnt[i1], 1);
        btok[i1 * N_TOK + p1] = n; bwt[i1 * N_TOK + p1] = w1;
        atomicAdd(&usage[i0], w0);
        atomicAdd(&usage[i1], w1);
    }
}

__global__ __launch_bounds__(256) void expert_fb_kernel(
    const float* __restrict__ x, const float* __restrict__ W1,
    const float* __restrict__ b1, const float* __restrict__ W2,
    const float* __restrict__ b2, const int* __restrict__ cnt,
    const int* __restrict__ btok, const float* __restrict__ bwt,
    float* __restrict__ out)
{
    __shared__ float xs[TN][DIM];
    __shared__ float h1s[TN][HC];
    __shared__ int   tok_s[TN];
    __shared__ float wt_s[TN];
    int e = blockIdx.x >> 8;
    int tile = blockIdx.x & 255;
    int cn = cnt[e];
    int n0 = tile * TN;
    if (n0 >= cn) return;
    int nt = min(TN, cn - n0);
    int tid = threadIdx.x;
    if (tid < TN) {
        if (tid < nt) { tok_s[tid] = btok[e * N_TOK + n0 + tid]; wt_s[tid] = bwt[e * N_TOK + n0 + tid]; }
        else          { tok_s[tid] = 0; wt_s[tid] = 0.f; }
    }
    __syncthreads();
    for (int idx = tid; idx < TN * DIM; idx += 256) {
        int t = idx >> 9, d = idx & 511;
        xs[t][d] = (t < nt) ? x[tok_s[t] * DIM + d] : 0.f;
    }
    const float* W1e = W1 + (size_t)e * DIM * HID;
    const float* W2e = W2 + (size_t)e * HID * DIM;
    int tg = tid >> 6, lane = tid & 63;
    float oacc[4][8];
    {
        float4 ba = *(const float4*)&b2[e * DIM + lane * 8];
        float4 bb = *(const float4*)&b2[e * DIM + lane * 8 + 4];
#pragma unroll
        for (int ti = 0; ti < 4; ++ti) {
            oacc[ti][0] = ba.x; oacc[ti][1] = ba.y; oacc[ti][2] = ba.z; oacc[ti][3] = ba.w;
            oacc[ti][4] = bb.x; oacc[ti][5] = bb.y; oacc[ti][6] = bb.z; oacc[ti][7] = bb.w;
        }
    }
    __syncthreads();
    for (int ch = 0; ch < NCHUNK; ++ch) {
        int h0 = ch * HC;
        float f[4][4];
        {
            float4 b1v = *(const float4*)&b1[e * HID + h0 + lane * 4];
#pragma unroll
            for (int ti = 0; ti < 4; ++ti) {
                f[ti][0] = b1v.x; f[ti][1] = b1v.y; f[ti][2] = b1v.z; f[ti][3] = b1v.w;
            }
        }
        for (int d = 0; d < DIM; ++d) {
            float4 w1v = *(const float4*)&W1e[(size_t)d * HID + h0 + lane * 4];
#pragma unroll
            for (int ti = 0; ti < 4; ++ti) {
                float xv = xs[tg + 4 * ti][d];
                f[ti][0] += xv * w1v.x; f[ti][1] += xv * w1v.y;
                f[ti][2] += xv * w1v.z; f[ti][3] += xv * w1v.w;
            }
        }
        __syncthreads();
#pragma unroll
        for (int ti = 0; ti < 4; ++ti)
            *(float4*)&h1s[tg + 4 * ti][lane * 4] = make_float4(f[ti][0], f[ti][1], f[ti][2], f[ti][3]);
        __syncthreads();
        for (int j = 0; j < HC; ++j) {
            const float* w2row = &W2e[(size_t)(h0 + j) * DIM + lane * 8];
            float4 wa = *(const float4*)w2row;
            float4 wb = *(const float4*)(w2row + 4);
#pragma unroll
            for (int ti = 0; ti < 4; ++ti) {
                float hv = h1s[tg + 4 * ti][j];
                oacc[ti][0] += hv * wa.x; oacc[ti][1] += hv * wa.y;
                oacc[ti][2] += hv * wa.z; oacc[ti][3] += hv * wa.w;
                oacc[ti][4] += hv * wb.x; oacc[ti][5] += hv * wb.y;
                oacc[ti][6] += hv * wb.z; oacc[ti][7] += hv * wb.w;
            }
        }
    }
#pragma unroll
    for (int ti = 0; ti < 4; ++ti) {
        int t = tg + 4 * ti;
        if (t < nt) {
            float w = wt_s[t];
            float* o = &out[(size_t)tok_s[t] * DIM + lane * 8];
#pragma unroll
            for (int c = 0; c < 8; ++c)
                atomicAdd(&o[c], w * oacc[ti][c]);
        }
    }
}

// ------------------------------------------------------------------ host ----
extern "C" void kernel_launch(void* const* d_in, const int* in_sizes, int n_in,
                              void* d_out, int out_size, void* d_ws, size_t ws_size,
                              hipStream_t stream) {
    const float* x  = (const float*)d_in[0];
    const float* Wg = (const float*)d_in[1];
    const float* bg = (const float*)d_in[2];
    const float* W1 = (const float*)d_in[3];
    const float* b1 = (const float*)d_in[4];
    const float* W2 = (const float*)d_in[5];
    const float* b2 = (const float*)d_in[6];

    float* out   = (float*)d_out;
    float* usage = out + (size_t)N_TOK * DIM;

    // ws layout (bf16 path)
    char* ws = (char*)d_ws;
    int*   cnt  = (int*)(ws + 0);
    int*   fill = (int*)(ws + 32);
    int*   offs = (int*)(ws + 64);
    unsigned short* tile_tab = (unsigned short*)(ws + 96);
    int*   ntile = (int*)(ws + 240);
    int*   te   = (int*)(ws + 256);
    float* tw   = (float*)(ws + 33024);
    int*   btok = (int*)(ws + 65792);
    float* bwt  = (float*)(ws + 98560);
    unsigned short* Xb  = (unsigned short*)(ws + 131328);
    unsigned short* W1t = (unsigned short*)(ws + 4325632);
    unsigned short* W2t = (unsigned short*)(ws + 21102848);
    unsigned short* H1  = (unsigned short*)(ws + 37880064);
    const size_t WS_NEED = 71434496ULL;

    hipMemsetAsync(d_out, 0, (size_t)(N_TOK * DIM + NEXP) * sizeof(float), stream);

    if (ws_size >= WS_NEED) {
        hipMemsetAsync(cnt, 0, 32, stream);
        cvtx_kernel<<<N_TOK * DIM / 1024, 256, 0, stream>>>(x, Xb);
        transpose_cvt_kernel<<<dim3(DIM / 64, HID / 64, NEXP), 256, 0, stream>>>(W1, W1t, DIM, HID);
        transpose_cvt_kernel<<<dim3(HID / 64, DIM / 64, NEXP), 256, 0, stream>>>(W2, W2t, HID, DIM);
        gating_kernel<<<N_TOK / 16, 256, 0, stream>>>(x, Wg, bg, cnt, te, tw, usage);
        prefix_kernel<<<1, 64, 0, stream>>>(cnt, offs, fill, tile_tab, ntile);
        scatter_kernel<<<N_TOK / 256, 256, 0, stream>>>(te, tw, offs, fill, btok, bwt);
        gemm1_kernel<<<dim3(MAXTILE, HID / 128), 256, 0, stream>>>(
            Xb, W1t, b1, cnt, offs, btok, tile_tab, ntile, H1);
        gemm2_kernel<<<dim3(MAXTILE, DIM / 128, KSPLIT), 256, 0, stream>>>(
            H1, W2t, b2, cnt, offs, btok, bwt, tile_tab, ntile, out);
    } else {
        // round-1 fp32 fallback (verified)
        int*   fcnt  = (int*)d_ws;
        int*   fbtok = (int*)((char*)d_ws + 256);
        float* fbwt  = (float*)((char*)d_ws + 256 + (size_t)NEXP * N_TOK * sizeof(int));
        hipMemsetAsync(d_ws, 0, 256, stream);
        gating_fb_kernel<<<N_TOK / 4, 256, 0, stream>>>(x, Wg, bg, fcnt, fbtok, fbwt, usage);
        expert_fb_kernel<<<NEXP * (N_TOK / TN), 256, 0, stream>>>(
            x, W1, b1, W2, b2, fcnt, fbtok, fbwt, out);
    }
}

// Round 8
// 223.890 us; speedup vs baseline: 1.5901x; 1.2108x over previous
//
#include <hip/hip_runtime.h>
#include <hip/hip_bf16.h>

// MoE: N=4096 tokens, D=512, H=2048, E=8 experts, top-2.
// Round 8: atomic-free gemm2. Round-7 showed device-scope atomicAdd resolves
// as HBM RMW (WRITE_SIZE == atomic payload; per-XCD L2 non-coherent), so the
// 67-MB atomic stream was gemm2's wall. Now gemm2 plain-stores bf16 partials
// O[kz][slot][512] into the dead W1t region (16.8 MB, free after gemm1) and a
// combine kernel sums 4 partial rows per token. Slot map reuses the te region
// (scatter: same-thread read-then-write). cvtx folded into gating; d_out
// memset shrunk to usage only. GEMM K-loops (BK=64, XOR swizzle, 0 conflicts)
// unchanged from round 7; KSPLIT back to 2.

#define N_TOK 4096
#define DIM   512
#define HID   2048
#define NEXP  8
#define TOTSLOT (2 * N_TOK)
#define MAXTILE 72

typedef __attribute__((ext_vector_type(8))) short short8;
typedef __attribute__((ext_vector_type(4))) float f32x4;

static __device__ __forceinline__ unsigned short f2bf(float f) {
    __hip_bfloat16 b = __float2bfloat16(f);
    return *reinterpret_cast<unsigned short*>(&b);
}
static __device__ __forceinline__ float bf2f(unsigned short u) {
    return __uint_as_float((unsigned)u << 16);
}

static __device__ __forceinline__ void load16_to_lds(const void* g, void* l) {
    __builtin_amdgcn_global_load_lds(
        (const __attribute__((address_space(1))) unsigned int*)g,
        (__attribute__((address_space(3))) unsigned int*)l, 16, 0, 0);
}

// ---------------------------------------------------------------- gating ----
// 256 blocks x 16 tokens; wave w handles tokens [w*4, w*4+4). Also converts
// x -> Xb bf16 on the fly (x is read fully here anyway).
__global__ __launch_bounds__(256) void gating_kernel(
    const float* __restrict__ x, const float* __restrict__ Wg,
    const float* __restrict__ bg,
    int* __restrict__ cnt, int* __restrict__ te, float* __restrict__ tw,
    float* __restrict__ usage, unsigned short* __restrict__ Xb)
{
    __shared__ int   lcnt[NEXP];
    __shared__ float lus[NEXP];
    int tid = threadIdx.x;
    if (tid < NEXP) { lcnt[tid] = 0; lus[tid] = 0.f; }
    __syncthreads();

    int wave = tid >> 6;
    int lane = tid & 63;

    for (int t = 0; t < 4; ++t) {
        int n = blockIdx.x * 16 + wave * 4 + t;

        float acc[NEXP];
#pragma unroll
        for (int e = 0; e < NEXP; ++e) acc[e] = 0.f;

#pragma unroll
        for (int it = 0; it < DIM / 64; ++it) {
            int d = it * 64 + lane;
            float xv = x[n * DIM + d];
            Xb[n * DIM + d] = f2bf(xv);
            float4 wa = *(const float4*)&Wg[d * NEXP];
            float4 wb = *(const float4*)&Wg[d * NEXP + 4];
            acc[0] += xv * wa.x; acc[1] += xv * wa.y;
            acc[2] += xv * wa.z; acc[3] += xv * wa.w;
            acc[4] += xv * wb.x; acc[5] += xv * wb.y;
            acc[6] += xv * wb.z; acc[7] += xv * wb.w;
        }
#pragma unroll
        for (int m = 32; m >= 1; m >>= 1) {
#pragma unroll
            for (int e = 0; e < NEXP; ++e)
                acc[e] += __shfl_xor(acc[e], m, 64);
        }
        if (lane == 0) {
            float l[NEXP];
#pragma unroll
            for (int e = 0; e < NEXP; ++e) l[e] = acc[e] + bg[e];
            int i0 = 0;
#pragma unroll
            for (int e = 1; e < NEXP; ++e) if (l[e] > l[i0]) i0 = e;
            int i1 = (i0 == 0) ? 1 : 0;
#pragma unroll
            for (int e = 0; e < NEXP; ++e)
                if (e != i0 && l[e] > l[i1]) i1 = e;
            float w0 = 1.f / (1.f + expf(l[i1] - l[i0]));
            float w1 = 1.f - w0;
            te[n * 2] = i0; te[n * 2 + 1] = i1;
            tw[n * 2] = w0; tw[n * 2 + 1] = w1;
            atomicAdd(&lcnt[i0], 1);
            atomicAdd(&lcnt[i1], 1);
            atomicAdd(&lus[i0], w0);
            atomicAdd(&lus[i1], w1);
        }
    }
    __syncthreads();
    if (tid < NEXP) {
        if (lcnt[tid]) atomicAdd(&cnt[tid], lcnt[tid]);
        if (lus[tid] != 0.f) atomicAdd(&usage[tid], lus[tid]);
    }
}

__global__ void prefix_kernel(const int* __restrict__ cnt,
                              int* __restrict__ offs, int* __restrict__ fill,
                              unsigned short* __restrict__ tile_tab,
                              int* __restrict__ ntile)
{
    if (threadIdx.x == 0) {
        int s = 0, nt = 0;
        for (int e = 0; e < NEXP; ++e) {
            offs[e] = s; s += cnt[e];
            int t = (cnt[e] + 127) >> 7;
            for (int i = 0; i < t; ++i)
                tile_tab[nt++] = (unsigned short)((e << 8) | i);
        }
        *ntile = nt;
        for (int i = nt; i < MAXTILE; ++i) tile_tab[i] = 0;
    }
    if (threadIdx.x < NEXP) fill[threadIdx.x] = 0;
}

// te is read (expert pair) then overwritten with the token's slot indices
// (same thread -> no hazard); combine_kernel consumes it as the slot map.
__global__ __launch_bounds__(256) void scatter_kernel(
    int* __restrict__ te, const float* __restrict__ tw,
    const int* __restrict__ offs, int* __restrict__ fill,
    int* __restrict__ btok, float* __restrict__ bwt)
{
    __shared__ int lcnt[NEXP];
    __shared__ int gbase[NEXP];
    int tid = threadIdx.x;
    if (tid < NEXP) lcnt[tid] = 0;
    __syncthreads();
    int n = blockIdx.x * 256 + tid;
    int e0 = te[n * 2], e1 = te[n * 2 + 1];
    int l0 = atomicAdd(&lcnt[e0], 1);
    int l1 = atomicAdd(&lcnt[e1], 1);
    __syncthreads();
    if (tid < NEXP) gbase[tid] = atomicAdd(&fill[tid], lcnt[tid]);
    __syncthreads();
    int s0 = offs[e0] + gbase[e0] + l0;
    int s1 = offs[e1] + gbase[e1] + l1;
    btok[s0] = n; bwt[s0] = tw[n * 2];
    btok[s1] = n; bwt[s1] = tw[n * 2 + 1];
    te[n * 2] = s0; te[n * 2 + 1] = s1;   // slot map for combine
}

// in: [E][R][C] fp32  ->  out: [E][C][R] bf16
__global__ __launch_bounds__(256) void transpose_cvt_kernel(
    const float* __restrict__ in, unsigned short* __restrict__ out,
    int R, int C)
{
    __shared__ unsigned short tile[64][65];
    int e = blockIdx.z;
    const float* src = in + (size_t)e * R * C;
    unsigned short* dst = out + (size_t)e * R * C;
    int r0 = blockIdx.x * 64, c0 = blockIdx.y * 64;
    int tid = threadIdx.x;
    int rr = tid >> 2, cb = (tid & 3) * 16;
#pragma unroll
    for (int i = 0; i < 4; ++i) {
        float4 v = *(const float4*)&src[(size_t)(r0 + rr) * C + c0 + cb + i * 4];
        tile[rr][cb + i * 4 + 0] = f2bf(v.x);
        tile[rr][cb + i * 4 + 1] = f2bf(v.y);
        tile[rr][cb + i * 4 + 2] = f2bf(v.z);
        tile[rr][cb + i * 4 + 3] = f2bf(v.w);
    }
    __syncthreads();
#pragma unroll
    for (int i = 0; i < 4; ++i) {
        ushort4 u;
        u.x = tile[cb + i * 4 + 0][rr];
        u.y = tile[cb + i * 4 + 1][rr];
        u.z = tile[cb + i * 4 + 2][rr];
        u.w = tile[cb + i * 4 + 3][rr];
        *(ushort4*)&dst[(size_t)(c0 + rr) * R + r0 + cb + i * 4] = u;
    }
}

// ------------------------------------------------------------- MFMA GEMM ----
// LDS: 128 rows x 64 bf16, chunk c of row R at physical c^(R&7) (0 bank
// conflicts, verified round 7). Staging via global_load_lds dwordx4.

__global__ __launch_bounds__(256) void gemm1_kernel(
    const unsigned short* __restrict__ Xb, const unsigned short* __restrict__ W1t,
    const float* __restrict__ b1, const int* __restrict__ cnt,
    const int* __restrict__ offs, const int* __restrict__ btok,
    const unsigned short* __restrict__ tile_tab, const int* __restrict__ ntile,
    unsigned short* __restrict__ H1)
{
    __shared__ __align__(16) unsigned short Ws[128 * 64];
    __shared__ __align__(16) unsigned short Xs[128 * 64];
    __shared__ int tok_s[128];

    int ti = blockIdx.x;
    if (ti >= *ntile) return;
    unsigned short tv = tile_tab[ti];
    int e = tv >> 8, tt = tv & 255, ht = blockIdx.y;
    int cn = cnt[e];
    int off_e = offs[e];
    int tid = threadIdx.x;

    if (tid < 128) {
        int lr = tt * 128 + tid;
        tok_s[tid] = (lr < cn) ? btok[off_e + lr] : 0;
    }
    __syncthreads();

    int wave = tid >> 6, lane = tid & 63;
    int mbase = (wave >> 1) * 64, nbase = (wave & 1) * 64;
    int quad = lane >> 4, lcol = lane & 15;
    f32x4 acc[4][4];
#pragma unroll
    for (int mi = 0; mi < 4; ++mi)
#pragma unroll
        for (int ni = 0; ni < 4; ++ni)
            acc[mi][ni] = (f32x4){0.f, 0.f, 0.f, 0.f};

    int Rb = tid >> 3, pc = tid & 7;
    const unsigned short* Wsrc = W1t + ((size_t)e * HID + ht * 128) * DIM;

    for (int k0 = 0; k0 < DIM; k0 += 64) {
#pragma unroll
        for (int p = 0; p < 4; ++p) {
            int R = Rb + p * 32;
            int c = pc ^ (R & 7);
            load16_to_lds(&Wsrc[(size_t)R * DIM + k0 + c * 8], &Ws[R * 64 + pc * 8]);
            load16_to_lds(&Xb[(size_t)tok_s[R] * DIM + k0 + c * 8], &Xs[R * 64 + pc * 8]);
        }
        __syncthreads();
#pragma unroll
        for (int h = 0; h < 2; ++h) {
            int cs = ((h * 4 + quad) ^ (lcol & 7)) * 8;
            short8 a[4], b[4];
#pragma unroll
            for (int i = 0; i < 4; ++i) {
                a[i] = *(const short8*)&Ws[(mbase + i * 16 + lcol) * 64 + cs];
                b[i] = *(const short8*)&Xs[(nbase + i * 16 + lcol) * 64 + cs];
            }
#pragma unroll
            for (int mi = 0; mi < 4; ++mi)
#pragma unroll
                for (int ni = 0; ni < 4; ++ni)
                    acc[mi][ni] = __builtin_amdgcn_mfma_f32_16x16x32_bf16(
                        a[mi], b[ni], acc[mi][ni], 0, 0, 0);
        }
        __syncthreads();
    }

    float4 bv[4];
#pragma unroll
    for (int mi = 0; mi < 4; ++mi)
        bv[mi] = *(const float4*)&b1[e * HID + ht * 128 + mbase + mi * 16 + quad * 4];
#pragma unroll
    for (int ni = 0; ni < 4; ++ni) {
        int tn = tt * 128 + nbase + ni * 16 + lcol;
        if (tn >= cn) continue;
        size_t srow = (size_t)(off_e + tn) * HID + ht * 128;
#pragma unroll
        for (int mi = 0; mi < 4; ++mi) {
            int hh = mbase + mi * 16 + quad * 4;
            ushort4 u;
            u.x = f2bf(acc[mi][ni][0] + bv[mi].x);
            u.y = f2bf(acc[mi][ni][1] + bv[mi].y);
            u.z = f2bf(acc[mi][ni][2] + bv[mi].z);
            u.w = f2bf(acc[mi][ni][3] + bv[mi].w);
            *(ushort4*)&H1[srow + hh] = u;
        }
    }
}

#define KSPLIT 2
#define KCH (HID / KSPLIT)

// Writes bf16 partials O[kz][slot][d] = w*(acc + bias[kz==0]) — plain stores,
// no atomics. O aliases the W1t region (dead after gemm1; same stream).
__global__ __launch_bounds__(256) void gemm2_kernel(
    const unsigned short* __restrict__ H1, const unsigned short* __restrict__ W2t,
    const float* __restrict__ b2, const int* __restrict__ cnt,
    const int* __restrict__ offs, const int* __restrict__ btok,
    const float* __restrict__ bwt,
    const unsigned short* __restrict__ tile_tab, const int* __restrict__ ntile,
    unsigned short* __restrict__ O)
{
    __shared__ __align__(16) unsigned short Ws[128 * 64];
    __shared__ __align__(16) unsigned short Hs[128 * 64];
    __shared__ float wt_s[128];

    int ti = blockIdx.x;
    if (ti >= *ntile) return;
    unsigned short tv = tile_tab[ti];
    int e = tv >> 8, tt = tv & 255, dt = blockIdx.y, kz = blockIdx.z;
    int cn = cnt[e];
    int off_e = offs[e];
    int sb = off_e + tt * 128;
    int tid = threadIdx.x;

    if (tid < 128) {
        int lr = tt * 128 + tid;
        wt_s[tid] = (lr < cn) ? bwt[off_e + lr] : 0.f;
    }
    __syncthreads();

    int wave = tid >> 6, lane = tid & 63;
    int mbase = (wave >> 1) * 64, nbase = (wave & 1) * 64;   // m=slot, n=d
    int quad = lane >> 4, lcol = lane & 15;
    f32x4 acc[4][4];
#pragma unroll
    for (int mi = 0; mi < 4; ++mi)
#pragma unroll
        for (int ni = 0; ni < 4; ++ni)
            acc[mi][ni] = (f32x4){0.f, 0.f, 0.f, 0.f};

    int Rb = tid >> 3, pc = tid & 7;
    const unsigned short* Wsrc = W2t + ((size_t)e * DIM + dt * 128) * HID;

    for (int k0 = kz * KCH; k0 < (kz + 1) * KCH; k0 += 64) {
#pragma unroll
        for (int p = 0; p < 4; ++p) {
            int R = Rb + p * 32;
            int c = pc ^ (R & 7);
            int sr = sb + R; if (sr > TOTSLOT - 1) sr = TOTSLOT - 1;
            load16_to_lds(&Wsrc[(size_t)R * HID + k0 + c * 8], &Ws[R * 64 + pc * 8]);
            load16_to_lds(&H1[(size_t)sr * HID + k0 + c * 8], &Hs[R * 64 + pc * 8]);
        }
        __syncthreads();
#pragma unroll
        for (int h = 0; h < 2; ++h) {
            int cs = ((h * 4 + quad) ^ (lcol & 7)) * 8;
            short8 a[4], b[4];
#pragma unroll
            for (int i = 0; i < 4; ++i) {
                a[i] = *(const short8*)&Hs[(mbase + i * 16 + lcol) * 64 + cs];  // A = slots
                b[i] = *(const short8*)&Ws[(nbase + i * 16 + lcol) * 64 + cs];  // B = d
            }
#pragma unroll
            for (int mi = 0; mi < 4; ++mi)
#pragma unroll
                for (int ni = 0; ni < 4; ++ni)
                    acc[mi][ni] = __builtin_amdgcn_mfma_f32_16x16x32_bf16(
                        a[mi], b[ni], acc[mi][ni], 0, 0, 0);
        }
        __syncthreads();
    }

    unsigned short* Oe = O + ((size_t)kz * TOTSLOT + sb) * DIM + dt * 128;
#pragma unroll
    for (int ni = 0; ni < 4; ++ni) {
        int dl = nbase + ni * 16 + lcol;
        float bv = (kz == 0) ? b2[e * DIM + dt * 128 + dl] : 0.f;
#pragma unroll
        for (int mi = 0; mi < 4; ++mi) {
            int rl = mbase + mi * 16 + quad * 4;
#pragma unroll
            for (int r = 0; r < 4; ++r) {
                int sl = rl + r;
                if (tt * 128 + sl < cn)
                    Oe[(size_t)sl * DIM + dl] = f2bf(wt_s[sl] * (acc[mi][ni][r] + bv));
            }
        }
    }
}

// out[n][d] = sum of 4 partial rows: O[kz][slot][d], kz in {0,1}, slot in
// token's 2 slots. 2 tokens/block, thread = 4 consecutive d.
__global__ __launch_bounds__(256) void combine_kernel(
    const unsigned short* __restrict__ O, const int* __restrict__ sidx,
    float* __restrict__ out)
{
    int tid = threadIdx.x;
    int n = blockIdx.x * 2 + (tid >> 7);
    int dd = (tid & 127) * 4;
    int s0 = sidx[n * 2], s1 = sidx[n * 2 + 1];
    ushort4 a = *(const ushort4*)&O[(size_t)s0 * DIM + dd];
    ushort4 b = *(const ushort4*)&O[((size_t)TOTSLOT + s0) * DIM + dd];
    ushort4 c = *(const ushort4*)&O[(size_t)s1 * DIM + dd];
    ushort4 d = *(const ushort4*)&O[((size_t)TOTSLOT + s1) * DIM + dd];
    float4 o;
    o.x = bf2f(a.x) + bf2f(b.x) + bf2f(c.x) + bf2f(d.x);
    o.y = bf2f(a.y) + bf2f(b.y) + bf2f(c.y) + bf2f(d.y);
    o.z = bf2f(a.z) + bf2f(b.z) + bf2f(c.z) + bf2f(d.z);
    o.w = bf2f(a.w) + bf2f(b.w) + bf2f(c.w) + bf2f(d.w);
    *(float4*)&out[(size_t)n * DIM + dd] = o;
}

// ------------------------------------------------- round-1 fp32 fallback ----
#define TN 16
#define HC 256
#define NCHUNK (HID / HC)

__global__ __launch_bounds__(256) void gating_fb_kernel(
    const float* __restrict__ x, const float* __restrict__ Wg,
    const float* __restrict__ bg,
    int* __restrict__ cnt, int* __restrict__ btok, float* __restrict__ bwt,
    float* __restrict__ usage)
{
    int wave = threadIdx.x >> 6;
    int lane = threadIdx.x & 63;
    int n = blockIdx.x * 4 + wave;
    float acc[NEXP];
#pragma unroll
    for (int e = 0; e < NEXP; ++e) acc[e] = 0.f;
    for (int d = lane; d < DIM; d += 64) {
        float xv = x[n * DIM + d];
        float4 wa = *(const float4*)&Wg[d * NEXP];
        float4 wb = *(const float4*)&Wg[d * NEXP + 4];
        acc[0] += xv * wa.x; acc[1] += xv * wa.y;
        acc[2] += xv * wa.z; acc[3] += xv * wa.w;
        acc[4] += xv * wb.x; acc[5] += xv * wb.y;
        acc[6] += xv * wb.z; acc[7] += xv * wb.w;
    }
#pragma unroll
    for (int m = 32; m >= 1; m >>= 1)
#pragma unroll
        for (int e = 0; e < NEXP; ++e)
            acc[e] += __shfl_xor(acc[e], m, 64);
    if (lane == 0) {
        float l[NEXP];
#pragma unroll
        for (int e = 0; e < NEXP; ++e) l[e] = acc[e] + bg[e];
        int i0 = 0;
#pragma unroll
        for (int e = 1; e < NEXP; ++e) if (l[e] > l[i0]) i0 = e;
        int i1 = (i0 == 0) ? 1 : 0;
#pragma unroll
        for (int e = 0; e < NEXP; ++e)
            if (e != i0 && l[e] > l[i1]) i1 = e;
        float w0 = 1.f / (1.f + expf(l[i1] - l[i0]));
        float w1 = 1.f - w0;
        int p0 = atomicAdd(&cnt[i0], 1);
        btok[i0 * N_TOK + p0] = n; bwt[i0 * N_TOK + p0] = w0;
        int p1 = atomicAdd(&cnt[i1], 1);
        btok[i1 * N_TOK + p1] = n; bwt[i1 * N_TOK + p1] = w1;
        atomicAdd(&usage[i0], w0);
        atomicAdd(&usage[i1], w1);
    }
}

__global__ __launch_bounds__(256) void expert_fb_kernel(
    const float* __restrict__ x, const float* __restrict__ W1,
    const float* __restrict__ b1, const float* __restrict__ W2,
    const float* __restrict__ b2, const int* __restrict__ cnt,
    const int* __restrict__ btok, const float* __restrict__ bwt,
    float* __restrict__ out)
{
    __shared__ float xs[TN][DIM];
    __shared__ float h1s[TN][HC];
    __shared__ int   tok_s[TN];
    __shared__ float wt_s[TN];
    int e = blockIdx.x >> 8;
    int tile = blockIdx.x & 255;
    int cn = cnt[e];
    int n0 = tile * TN;
    if (n0 >= cn) return;
    int nt = min(TN, cn - n0);
    int tid = threadIdx.x;
    if (tid < TN) {
        if (tid < nt) { tok_s[tid] = btok[e * N_TOK + n0 + tid]; wt_s[tid] = bwt[e * N_TOK + n0 + tid]; }
        else          { tok_s[tid] = 0; wt_s[tid] = 0.f; }
    }
    __syncthreads();
    for (int idx = tid; idx < TN * DIM; idx += 256) {
        int t = idx >> 9, d = idx & 511;
        xs[t][d] = (t < nt) ? x[tok_s[t] * DIM + d] : 0.f;
    }
    const float* W1e = W1 + (size_t)e * DIM * HID;
    const float* W2e = W2 + (size_t)e * HID * DIM;
    int tg = tid >> 6, lane = tid & 63;
    float oacc[4][8];
    {
        float4 ba = *(const float4*)&b2[e * DIM + lane * 8];
        float4 bb = *(const float4*)&b2[e * DIM + lane * 8 + 4];
#pragma unroll
        for (int ti = 0; ti < 4; ++ti) {
            oacc[ti][0] = ba.x; oacc[ti][1] = ba.y; oacc[ti][2] = ba.z; oacc[ti][3] = ba.w;
            oacc[ti][4] = bb.x; oacc[ti][5] = bb.y; oacc[ti][6] = bb.z; oacc[ti][7] = bb.w;
        }
    }
    __syncthreads();
    for (int ch = 0; ch < NCHUNK; ++ch) {
        int h0 = ch * HC;
        float f[4][4];
        {
            float4 b1v = *(const float4*)&b1[e * HID + h0 + lane * 4];
#pragma unroll
            for (int ti = 0; ti < 4; ++ti) {
                f[ti][0] = b1v.x; f[ti][1] = b1v.y; f[ti][2] = b1v.z; f[ti][3] = b1v.w;
            }
        }
        for (int d = 0; d < DIM; ++d) {
            float4 w1v = *(const float4*)&W1e[(size_t)d * HID + h0 + lane * 4];
#pragma unroll
            for (int ti = 0; ti < 4; ++ti) {
                float xv = xs[tg + 4 * ti][d];
                f[ti][0] += xv * w1v.x; f[ti][1] += xv * w1v.y;
                f[ti][2] += xv * w1v.z; f[ti][3] += xv * w1v.w;
            }
        }
        __syncthreads();
#pragma unroll
        for (int ti = 0; ti < 4; ++ti)
            *(float4*)&h1s[tg + 4 * ti][lane * 4] = make_float4(f[ti][0], f[ti][1], f[ti][2], f[ti][3]);
        __syncthreads();
        for (int j = 0; j < HC; ++j) {
            const float* w2row = &W2e[(size_t)(h0 + j) * DIM + lane * 8];
            float4 wa = *(const float4*)w2row;
            float4 wb = *(const float4*)(w2row + 4);
#pragma unroll
            for (int ti = 0; ti < 4; ++ti) {
                float hv = h1s[tg + 4 * ti][j];
                oacc[ti][0] += hv * wa.x; oacc[ti][1] += hv * wa.y;
                oacc[ti][2] += hv * wa.z; oacc[ti][3] += hv * wa.w;
                oacc[ti][4] += hv * wb.x; oacc[ti][5] += hv * wb.y;
                oacc[ti][6] += hv * wb.z; oacc[ti][7] += hv * wb.w;
            }
        }
    }
#pragma unroll
    for (int ti = 0; ti < 4; ++ti) {
        int t = tg + 4 * ti;
        if (t < nt) {
            float w = wt_s[t];
            float* o = &out[(size_t)tok_s[t] * DIM + lane * 8];
#pragma unroll
            for (int c = 0; c < 8; ++c)
                atomicAdd(&o[c], w * oacc[ti][c]);
        }
    }
}

// ------------------------------------------------------------------ host ----
extern "C" void kernel_launch(void* const* d_in, const int* in_sizes, int n_in,
                              void* d_out, int out_size, void* d_ws, size_t ws_size,
                              hipStream_t stream) {
    const float* x  = (const float*)d_in[0];
    const float* Wg = (const float*)d_in[1];
    const float* bg = (const float*)d_in[2];
    const float* W1 = (const float*)d_in[3];
    const float* b1 = (const float*)d_in[4];
    const float* W2 = (const float*)d_in[5];
    const float* b2 = (const float*)d_in[6];

    float* out   = (float*)d_out;
    float* usage = out + (size_t)N_TOK * DIM;

    // ws layout (bf16 path). O (gemm2 bf16 partials, 2*8192*512*2 = 16.8 MB)
    // aliases W1t: W1t dead after gemm1, same-stream ordering makes it safe.
    char* ws = (char*)d_ws;
    int*   cnt  = (int*)(ws + 0);
    int*   fill = (int*)(ws + 32);
    int*   offs = (int*)(ws + 64);
    unsigned short* tile_tab = (unsigned short*)(ws + 96);
    int*   ntile = (int*)(ws + 240);
    int*   te   = (int*)(ws + 256);       // expert pair, then slot map
    float* tw   = (float*)(ws + 33024);
    int*   btok = (int*)(ws + 65792);
    float* bwt  = (float*)(ws + 98560);
    unsigned short* Xb  = (unsigned short*)(ws + 131328);
    unsigned short* W1t = (unsigned short*)(ws + 4325632);
    unsigned short* O   = W1t;            // alias (see above)
    unsigned short* W2t = (unsigned short*)(ws + 21102848);
    unsigned short* H1  = (unsigned short*)(ws + 37880064);
    const size_t WS_NEED = 71434496ULL;

    if (ws_size >= WS_NEED) {
        hipMemsetAsync(cnt, 0, 32, stream);
        hipMemsetAsync(usage, 0, NEXP * sizeof(float), stream);  // combine overwrites combined
        transpose_cvt_kernel<<<dim3(DIM / 64, HID / 64, NEXP), 256, 0, stream>>>(W1, W1t, DIM, HID);
        transpose_cvt_kernel<<<dim3(HID / 64, DIM / 64, NEXP), 256, 0, stream>>>(W2, W2t, HID, DIM);
        gating_kernel<<<N_TOK / 16, 256, 0, stream>>>(x, Wg, bg, cnt, te, tw, usage, Xb);
        prefix_kernel<<<1, 64, 0, stream>>>(cnt, offs, fill, tile_tab, ntile);
        scatter_kernel<<<N_TOK / 256, 256, 0, stream>>>(te, tw, offs, fill, btok, bwt);
        gemm1_kernel<<<dim3(MAXTILE, HID / 128), 256, 0, stream>>>(
            Xb, W1t, b1, cnt, offs, btok, tile_tab, ntile, H1);
        gemm2_kernel<<<dim3(MAXTILE, DIM / 128, KSPLIT), 256, 0, stream>>>(
            H1, W2t, b2, cnt, offs, btok, bwt, tile_tab, ntile, O);
        combine_kernel<<<N_TOK / 2, 256, 0, stream>>>(O, te, out);
    } else {
        // round-1 fp32 fallback (verified)
        int*   fcnt  = (int*)d_ws;
        int*   fbtok = (int*)((char*)d_ws + 256);
        float* fbwt  = (float*)((char*)d_ws + 256 + (size_t)NEXP * N_TOK * sizeof(int));
        hipMemsetAsync(d_out, 0, (size_t)(N_TOK * DIM + NEXP) * sizeof(float), stream);
        hipMemsetAsync(d_ws, 0, 256, stream);
        gating_fb_kernel<<<N_TOK / 4, 256, 0, stream>>>(x, Wg, bg, fcnt, fbtok, fbwt, usage);
        expert_fb_kernel<<<NEXP * (N_TOK / TN), 256, 0, stream>>>(
            x, W1, b1, W2, b2, fcnt, fbtok, fbwt, out);
    }
}